// Round 1
// baseline (1518.212 us; speedup 1.0000x reference)
//
#include <hip/hip_runtime.h>

#define NEG_SLOPE 0.2f

// ---- monotone float<->uint encoding so atomicMax(uint) == max(float),
//      and memset(0) == -inf-like sentinel (decodes to -NaN, below all reals)
__device__ __forceinline__ unsigned fenc(float f) {
    unsigned b = __float_as_uint(f);
    return (b & 0x80000000u) ? ~b : (b | 0x80000000u);
}
__device__ __forceinline__ float fdec(unsigned u) {
    return __uint_as_float((u & 0x80000000u) ? (u ^ 0x80000000u) : ~u);
}

__device__ __forceinline__ float leaky(float v) {
    return v > 0.0f ? v : NEG_SLOPE * v;
}
__device__ __forceinline__ float elu(float v) {
    return v > 0.0f ? v : (__expf(v) - 1.0f);
}

// ================= GEMM1: H[N,64] = X[N,512] @ W[512,64] =================
__global__ __launch_bounds__(256) void gemm1_k(const float* __restrict__ X,
                                               const float* __restrict__ W,
                                               float* __restrict__ H, int N) {
    __shared__ float As[64][20];   // 64 rows x 16 k (+4 pad, keeps float4 align)
    __shared__ float Bs[16][64];
    const int t = threadIdx.x;
    const int tx = t & 15, ty = t >> 4;
    const int r0 = blockIdx.x * 64;
    float acc[4][4] = {};

    for (int k0 = 0; k0 < 512; k0 += 16) {
        { // A tile: 64x16, 4 floats/thread
            int r = t >> 2, cg = (t & 3) * 4;
            int row = r0 + r; if (row >= N) row = N - 1;
            float4 v = *(const float4*)(X + (size_t)row * 512 + k0 + cg);
            *(float4*)&As[r][cg] = v;
        }
        { // B tile: 16x64, 4 floats/thread
            int r = t >> 4, cg = (t & 15) * 4;
            float4 v = *(const float4*)(W + (size_t)(k0 + r) * 64 + cg);
            *(float4*)&Bs[r][cg] = v;
        }
        __syncthreads();
#pragma unroll
        for (int kk = 0; kk < 16; ++kk) {
            float a0 = As[ty * 4 + 0][kk], a1 = As[ty * 4 + 1][kk];
            float a2 = As[ty * 4 + 2][kk], a3 = As[ty * 4 + 3][kk];
            float4 b = *(float4*)&Bs[kk][tx * 4];
            acc[0][0] += a0 * b.x; acc[0][1] += a0 * b.y; acc[0][2] += a0 * b.z; acc[0][3] += a0 * b.w;
            acc[1][0] += a1 * b.x; acc[1][1] += a1 * b.y; acc[1][2] += a1 * b.z; acc[1][3] += a1 * b.w;
            acc[2][0] += a2 * b.x; acc[2][1] += a2 * b.y; acc[2][2] += a2 * b.z; acc[2][3] += a2 * b.w;
            acc[3][0] += a3 * b.x; acc[3][1] += a3 * b.y; acc[3][2] += a3 * b.z; acc[3][3] += a3 * b.w;
        }
        __syncthreads();
    }
#pragma unroll
    for (int i = 0; i < 4; ++i) {
        int row = r0 + ty * 4 + i;
        if (row < N) {
            float4 v = make_float4(acc[i][0], acc[i][1], acc[i][2], acc[i][3]);
            *(float4*)&H[(size_t)row * 64 + tx * 4] = v;
        }
    }
}

// ================= GEMM2: H2[N,128] = A[N,64] @ W[64,128] =================
__global__ __launch_bounds__(256) void gemm2_k(const float* __restrict__ X,
                                               const float* __restrict__ W,
                                               float* __restrict__ H, int N) {
    __shared__ float As[64][20];
    __shared__ float Bs[16][128];
    const int t = threadIdx.x;
    const int tx = t & 15, ty = t >> 4;
    const int r0 = blockIdx.x * 64;
    float acc[4][8] = {};

    for (int k0 = 0; k0 < 64; k0 += 16) {
        {
            int r = t >> 2, cg = (t & 3) * 4;
            int row = r0 + r; if (row >= N) row = N - 1;
            float4 v = *(const float4*)(X + (size_t)row * 64 + k0 + cg);
            *(float4*)&As[r][cg] = v;
        }
#pragma unroll
        for (int u = 0; u < 2; ++u) { // B tile: 16x128, 8 floats/thread
            int lin = t + u * 256;
            int r = lin >> 5, cg = (lin & 31) * 4;
            float4 v = *(const float4*)(W + (size_t)(k0 + r) * 128 + cg);
            *(float4*)&Bs[r][cg] = v;
        }
        __syncthreads();
#pragma unroll
        for (int kk = 0; kk < 16; ++kk) {
            float a[4];
#pragma unroll
            for (int i = 0; i < 4; ++i) a[i] = As[ty * 4 + i][kk];
            float4 b0 = *(float4*)&Bs[kk][tx * 8];
            float4 b1 = *(float4*)&Bs[kk][tx * 8 + 4];
#pragma unroll
            for (int i = 0; i < 4; ++i) {
                acc[i][0] += a[i] * b0.x; acc[i][1] += a[i] * b0.y;
                acc[i][2] += a[i] * b0.z; acc[i][3] += a[i] * b0.w;
                acc[i][4] += a[i] * b1.x; acc[i][5] += a[i] * b1.y;
                acc[i][6] += a[i] * b1.z; acc[i][7] += a[i] * b1.w;
            }
        }
        __syncthreads();
    }
#pragma unroll
    for (int i = 0; i < 4; ++i) {
        int row = r0 + ty * 4 + i;
        if (row < N) {
            *(float4*)&H[(size_t)row * 128 + tx * 8] =
                make_float4(acc[i][0], acc[i][1], acc[i][2], acc[i][3]);
            *(float4*)&H[(size_t)row * 128 + tx * 8 + 4] =
                make_float4(acc[i][4], acc[i][5], acc[i][6], acc[i][7]);
        }
    }
}

// ========= per-node attention dots for conv1: s[n,h], d[n,h] (H=8,C=8) =========
__global__ void s1d1_k(const float* __restrict__ H, const float* __restrict__ Asrc,
                       const float* __restrict__ Adst, float* __restrict__ S,
                       float* __restrict__ D, int N) {
    int t = blockIdx.x * blockDim.x + threadIdx.x;
    if (t >= N * 8) return;
    int n = t >> 3, h = t & 7;
    const float4* hp = (const float4*)(H + (size_t)n * 64 + h * 8);
    float4 h0 = hp[0], h1 = hp[1];
    const float4* sp = (const float4*)(Asrc + h * 8);
    const float4* dp = (const float4*)(Adst + h * 8);
    float4 a0 = sp[0], a1 = sp[1], b0 = dp[0], b1 = dp[1];
    S[t] = h0.x * a0.x + h0.y * a0.y + h0.z * a0.z + h0.w * a0.w +
           h1.x * a1.x + h1.y * a1.y + h1.z * a1.z + h1.w * a1.w;
    D[t] = h0.x * b0.x + h0.y * b0.y + h0.z * b0.z + h0.w * b0.w +
           h1.x * b1.x + h1.y * b1.y + h1.z * b1.z + h1.w * b1.w;
}

__device__ __forceinline__ void edge_sd(const int* ei, int E, int e, int& src, int& dst) {
    if (e < E) { src = ei[e]; dst = ei[E + e]; }
    else       { src = dst = e - E; }
}

// ========= conv1 edge pass A: segment max (encoded) =========
__global__ void edge_max1_k(const int* __restrict__ ei, int E, int Etot,
                            const float* __restrict__ S, const float* __restrict__ D,
                            unsigned* __restrict__ amax) {
    int e = blockIdx.x * blockDim.x + threadIdx.x;
    if (e >= Etot) return;
    int src, dst; edge_sd(ei, E, e, src, dst);
#pragma unroll
    for (int h = 0; h < 8; ++h) {
        float v = leaky(S[(size_t)src * 8 + h] + D[(size_t)dst * 8 + h]);
        atomicMax(&amax[(size_t)dst * 8 + h], fenc(v));
    }
}

// ========= conv1 edge pass B: denom =========
__global__ void edge_den1_k(const int* __restrict__ ei, int E, int Etot,
                            const float* __restrict__ S, const float* __restrict__ D,
                            const unsigned* __restrict__ amax, float* __restrict__ den) {
    int e = blockIdx.x * blockDim.x + threadIdx.x;
    if (e >= Etot) return;
    int src, dst; edge_sd(ei, E, e, src, dst);
#pragma unroll
    for (int h = 0; h < 8; ++h) {
        float v = leaky(S[(size_t)src * 8 + h] + D[(size_t)dst * 8 + h]);
        float ea = __expf(v - fdec(amax[(size_t)dst * 8 + h]));
        atomicAdd(&den[(size_t)dst * 8 + h], ea);
    }
}

// ========= conv1 edge pass C: weighted scatter (1 wave = 1 edge, lane = channel) =========
__global__ void edge_agg1_k(const int* __restrict__ ei, int E, int Etot,
                            const float* __restrict__ S, const float* __restrict__ D,
                            const unsigned* __restrict__ amax, const float* __restrict__ den,
                            const float* __restrict__ H, float* __restrict__ out) {
    int t = blockIdx.x * blockDim.x + threadIdx.x;
    int e = t >> 6;
    if (e >= Etot) return;
    int j = t & 63, h = j >> 3;
    int src, dst; edge_sd(ei, E, e, src, dst);
    float v = leaky(S[(size_t)src * 8 + h] + D[(size_t)dst * 8 + h]);
    float ea = __expf(v - fdec(amax[(size_t)dst * 8 + h]));
    float w = ea / (den[(size_t)dst * 8 + h] + 1e-16f);
    atomicAdd(&out[(size_t)dst * 64 + j], H[(size_t)src * 64 + j] * w);
}

// ========= bias + ELU elementwise (mask = C-1, C power of 2) =========
__global__ void bias_elu_k(float* __restrict__ buf, const float* __restrict__ bias,
                           int mask, int total) {
    int t = blockIdx.x * blockDim.x + threadIdx.x;
    if (t >= total) return;
    buf[t] = elu(buf[t] + bias[t & mask]);
}

// ========= per-node attention dots for conv2 (H=1,C=128): 1 wave per node =========
__global__ void s2d2_k(const float* __restrict__ H, const float* __restrict__ Asrc,
                       const float* __restrict__ Adst, float* __restrict__ S,
                       float* __restrict__ D, int N) {
    int t = blockIdx.x * blockDim.x + threadIdx.x;
    int n = t >> 6, lane = t & 63;
    if (n >= N) return;
    const float* row = H + (size_t)n * 128;
    float s = row[lane] * Asrc[lane] + row[lane + 64] * Asrc[lane + 64];
    float d = row[lane] * Adst[lane] + row[lane + 64] * Adst[lane + 64];
#pragma unroll
    for (int off = 32; off > 0; off >>= 1) {
        s += __shfl_down(s, off);
        d += __shfl_down(d, off);
    }
    if (lane == 0) { S[n] = s; D[n] = d; }
}

// ========= conv2 edge passes (1 head) =========
__global__ void edge_max2_k(const int* __restrict__ ei, int E, int Etot,
                            const float* __restrict__ S, const float* __restrict__ D,
                            unsigned* __restrict__ amax) {
    int e = blockIdx.x * blockDim.x + threadIdx.x;
    if (e >= Etot) return;
    int src, dst; edge_sd(ei, E, e, src, dst);
    float v = leaky(S[src] + D[dst]);
    atomicMax(&amax[dst], fenc(v));
}

__global__ void edge_den2_k(const int* __restrict__ ei, int E, int Etot,
                            const float* __restrict__ S, const float* __restrict__ D,
                            const unsigned* __restrict__ amax, float* __restrict__ den) {
    int e = blockIdx.x * blockDim.x + threadIdx.x;
    if (e >= Etot) return;
    int src, dst; edge_sd(ei, E, e, src, dst);
    float v = leaky(S[src] + D[dst]);
    atomicAdd(&den[dst], __expf(v - fdec(amax[dst])));
}

// lane = channel (128 ch => 2 waves per edge)
__global__ void edge_agg2_k(const int* __restrict__ ei, int E, int Etot,
                            const float* __restrict__ S, const float* __restrict__ D,
                            const unsigned* __restrict__ amax, const float* __restrict__ den,
                            const float* __restrict__ H, float* __restrict__ out) {
    int t = blockIdx.x * blockDim.x + threadIdx.x;
    int e = t >> 7;
    if (e >= Etot) return;
    int c = t & 127;
    int src, dst; edge_sd(ei, E, e, src, dst);
    float v = leaky(S[src] + D[dst]);
    float ea = __expf(v - fdec(amax[dst]));
    float w = ea / (den[dst] + 1e-16f);
    atomicAdd(&out[(size_t)dst * 128 + c], H[(size_t)src * 128 + c] * w);
}

extern "C" void kernel_launch(void* const* d_in, const int* in_sizes, int n_in,
                              void* d_out, int out_size, void* d_ws, size_t ws_size,
                              hipStream_t stream) {
    const float* x   = (const float*)d_in[0];
    const int*   ei  = (const int*)d_in[1];
    const float* W1  = (const float*)d_in[2];
    const float* as1 = (const float*)d_in[3];
    const float* ad1 = (const float*)d_in[4];
    const float* b1  = (const float*)d_in[5];
    const float* W2  = (const float*)d_in[6];
    const float* as2 = (const float*)d_in[7];
    const float* ad2 = (const float*)d_in[8];
    const float* b2  = (const float*)d_in[9];

    const int N = in_sizes[0] / 512;
    const int E = in_sizes[1] / 2;
    const int Etot = E + N;
    float* out = (float*)d_out;

    // workspace layout (fp32 words)
    float*    h1    = (float*)d_ws;                       // N*64
    float*    s1    = h1 + (size_t)N * 64;                // N*8
    float*    d1    = s1 + (size_t)N * 8;                 // N*8
    unsigned* amax1 = (unsigned*)(d1 + (size_t)N * 8);    // N*8
    float*    den1  = (float*)(amax1 + (size_t)N * 8);    // N*8
    float*    out1  = den1 + (size_t)N * 8;               // N*64
    float*    h2    = out1 + (size_t)N * 64;              // N*128
    float*    s2    = h2 + (size_t)N * 128;               // N
    float*    d2    = s2 + N;                             // N
    unsigned* amax2 = (unsigned*)(d2 + N);                // N
    float*    den2  = (float*)(amax2 + N);                // N

    hipMemsetAsync(amax1, 0, (size_t)N * 8 * 4, stream);
    hipMemsetAsync(den1,  0, (size_t)N * 8 * 4, stream);
    hipMemsetAsync(out1,  0, (size_t)N * 64 * 4, stream);
    hipMemsetAsync(amax2, 0, (size_t)N * 4, stream);
    hipMemsetAsync(den2,  0, (size_t)N * 4, stream);
    hipMemsetAsync(out,   0, (size_t)out_size * 4, stream);

    const int B = 256;
    gemm1_k<<<(N + 63) / 64, B, 0, stream>>>(x, W1, h1, N);
    s1d1_k<<<(N * 8 + B - 1) / B, B, 0, stream>>>(h1, as1, ad1, s1, d1, N);
    edge_max1_k<<<(Etot + B - 1) / B, B, 0, stream>>>(ei, E, Etot, s1, d1, amax1);
    edge_den1_k<<<(Etot + B - 1) / B, B, 0, stream>>>(ei, E, Etot, s1, d1, amax1, den1);
    edge_agg1_k<<<(Etot * 64 + B - 1) / B, B, 0, stream>>>(ei, E, Etot, s1, d1, amax1, den1, h1, out1);
    bias_elu_k<<<(N * 64 + B - 1) / B, B, 0, stream>>>(out1, b1, 63, N * 64);
    gemm2_k<<<(N + 63) / 64, B, 0, stream>>>(out1, W2, h2, N);
    s2d2_k<<<(N * 64 + B - 1) / B, B, 0, stream>>>(h2, as2, ad2, s2, d2, N);
    edge_max2_k<<<(Etot + B - 1) / B, B, 0, stream>>>(ei, E, Etot, s2, d2, amax2);
    edge_den2_k<<<(Etot + B - 1) / B, B, 0, stream>>>(ei, E, Etot, s2, d2, amax2, den2);
    edge_agg2_k<<<(Etot * 128 + B - 1) / B, B, 0, stream>>>(ei, E, Etot, s2, d2, amax2, den2, h2, out);
    bias_elu_k<<<(N * 128 + B - 1) / B, B, 0, stream>>>(out, b2, 127, N * 128);
}

// Round 2
// 540.738 us; speedup vs baseline: 2.8077x; 2.8077x over previous
//
#include <hip/hip_runtime.h>

#define NEG_SLOPE 0.2f

__device__ __forceinline__ float leaky(float v) {
    return v > 0.0f ? v : NEG_SLOPE * v;
}
__device__ __forceinline__ float elu(float v) {
    return v > 0.0f ? v : (__expf(v) - 1.0f);
}

// ================= GEMM1: H[N,64] = X[N,512] @ W[512,64] =================
__global__ __launch_bounds__(256) void gemm1_k(const float* __restrict__ X,
                                               const float* __restrict__ W,
                                               float* __restrict__ H, int N) {
    __shared__ float As[64][20];
    __shared__ float Bs[16][64];
    const int t = threadIdx.x;
    const int tx = t & 15, ty = t >> 4;
    const int r0 = blockIdx.x * 64;
    float acc[4][4] = {};

    for (int k0 = 0; k0 < 512; k0 += 16) {
        {
            int r = t >> 2, cg = (t & 3) * 4;
            int row = r0 + r; if (row >= N) row = N - 1;
            float4 v = *(const float4*)(X + (size_t)row * 512 + k0 + cg);
            *(float4*)&As[r][cg] = v;
        }
        {
            int r = t >> 4, cg = (t & 15) * 4;
            float4 v = *(const float4*)(W + (size_t)(k0 + r) * 64 + cg);
            *(float4*)&Bs[r][cg] = v;
        }
        __syncthreads();
#pragma unroll
        for (int kk = 0; kk < 16; ++kk) {
            float a0 = As[ty * 4 + 0][kk], a1 = As[ty * 4 + 1][kk];
            float a2 = As[ty * 4 + 2][kk], a3 = As[ty * 4 + 3][kk];
            float4 b = *(float4*)&Bs[kk][tx * 4];
            acc[0][0] += a0 * b.x; acc[0][1] += a0 * b.y; acc[0][2] += a0 * b.z; acc[0][3] += a0 * b.w;
            acc[1][0] += a1 * b.x; acc[1][1] += a1 * b.y; acc[1][2] += a1 * b.z; acc[1][3] += a1 * b.w;
            acc[2][0] += a2 * b.x; acc[2][1] += a2 * b.y; acc[2][2] += a2 * b.z; acc[2][3] += a2 * b.w;
            acc[3][0] += a3 * b.x; acc[3][1] += a3 * b.y; acc[3][2] += a3 * b.z; acc[3][3] += a3 * b.w;
        }
        __syncthreads();
    }
#pragma unroll
    for (int i = 0; i < 4; ++i) {
        int row = r0 + ty * 4 + i;
        if (row < N) {
            float4 v = make_float4(acc[i][0], acc[i][1], acc[i][2], acc[i][3]);
            *(float4*)&H[(size_t)row * 64 + tx * 4] = v;
        }
    }
}

// ================= GEMM2: H2[N,128] = A[N,64] @ W[64,128] =================
__global__ __launch_bounds__(256) void gemm2_k(const float* __restrict__ X,
                                               const float* __restrict__ W,
                                               float* __restrict__ H, int N) {
    __shared__ float As[64][20];
    __shared__ float Bs[16][128];
    const int t = threadIdx.x;
    const int tx = t & 15, ty = t >> 4;
    const int r0 = blockIdx.x * 64;
    float acc[4][8] = {};

    for (int k0 = 0; k0 < 64; k0 += 16) {
        {
            int r = t >> 2, cg = (t & 3) * 4;
            int row = r0 + r; if (row >= N) row = N - 1;
            float4 v = *(const float4*)(X + (size_t)row * 64 + k0 + cg);
            *(float4*)&As[r][cg] = v;
        }
#pragma unroll
        for (int u = 0; u < 2; ++u) {
            int lin = t + u * 256;
            int r = lin >> 5, cg = (lin & 31) * 4;
            float4 v = *(const float4*)(W + (size_t)(k0 + r) * 128 + cg);
            *(float4*)&Bs[r][cg] = v;
        }
        __syncthreads();
#pragma unroll
        for (int kk = 0; kk < 16; ++kk) {
            float a[4];
#pragma unroll
            for (int i = 0; i < 4; ++i) a[i] = As[ty * 4 + i][kk];
            float4 b0 = *(float4*)&Bs[kk][tx * 8];
            float4 b1 = *(float4*)&Bs[kk][tx * 8 + 4];
#pragma unroll
            for (int i = 0; i < 4; ++i) {
                acc[i][0] += a[i] * b0.x; acc[i][1] += a[i] * b0.y;
                acc[i][2] += a[i] * b0.z; acc[i][3] += a[i] * b0.w;
                acc[i][4] += a[i] * b1.x; acc[i][5] += a[i] * b1.y;
                acc[i][6] += a[i] * b1.z; acc[i][7] += a[i] * b1.w;
            }
        }
        __syncthreads();
    }
#pragma unroll
    for (int i = 0; i < 4; ++i) {
        int row = r0 + ty * 4 + i;
        if (row < N) {
            *(float4*)&H[(size_t)row * 128 + tx * 8] =
                make_float4(acc[i][0], acc[i][1], acc[i][2], acc[i][3]);
            *(float4*)&H[(size_t)row * 128 + tx * 8 + 4] =
                make_float4(acc[i][4], acc[i][5], acc[i][6], acc[i][7]);
        }
    }
}

// ========= per-node attention dots for conv1: s[n,h], d[n,h] (H=8,C=8) =========
__global__ void s1d1_k(const float* __restrict__ H, const float* __restrict__ Asrc,
                       const float* __restrict__ Adst, float* __restrict__ S,
                       float* __restrict__ D, int N) {
    int t = blockIdx.x * blockDim.x + threadIdx.x;
    if (t >= N * 8) return;
    int n = t >> 3, h = t & 7;
    const float4* hp = (const float4*)(H + (size_t)n * 64 + h * 8);
    float4 h0 = hp[0], h1 = hp[1];
    const float4* sp = (const float4*)(Asrc + h * 8);
    const float4* dp = (const float4*)(Adst + h * 8);
    float4 a0 = sp[0], a1 = sp[1], b0 = dp[0], b1 = dp[1];
    S[t] = h0.x * a0.x + h0.y * a0.y + h0.z * a0.z + h0.w * a0.w +
           h1.x * a1.x + h1.y * a1.y + h1.z * a1.z + h1.w * a1.w;
    D[t] = h0.x * b0.x + h0.y * b0.y + h0.z * b0.z + h0.w * b0.w +
           h1.x * b1.x + h1.y * b1.y + h1.z * b1.z + h1.w * b1.w;
}

// ========= per-node attention dots for conv2 (H=1,C=128): 1 wave per node =========
__global__ void s2d2_k(const float* __restrict__ H, const float* __restrict__ Asrc,
                       const float* __restrict__ Adst, float* __restrict__ S,
                       float* __restrict__ D, int N) {
    int t = blockIdx.x * blockDim.x + threadIdx.x;
    int n = t >> 6, lane = t & 63;
    if (n >= N) return;
    const float* row = H + (size_t)n * 128;
    float s = row[lane] * Asrc[lane] + row[lane + 64] * Asrc[lane + 64];
    float d = row[lane] * Adst[lane] + row[lane + 64] * Adst[lane + 64];
#pragma unroll
    for (int off = 32; off > 0; off >>= 1) {
        s += __shfl_down(s, off);
        d += __shfl_down(d, off);
    }
    if (lane == 0) { S[n] = s; D[n] = d; }
}

// ======================= CSR build =======================
__device__ __forceinline__ void edge_sd(const int* ei, int E, int e, int& src, int& dst) {
    if (e < E) { src = ei[e]; dst = ei[E + e]; }
    else       { src = dst = e - E; }
}

__global__ void deg_k(const int* __restrict__ ei, int E, int Etot, int* __restrict__ deg) {
    int e = blockIdx.x * blockDim.x + threadIdx.x;
    if (e >= Etot) return;
    int src, dst; edge_sd(ei, E, e, src, dst);
    atomicAdd(&deg[dst], 1);
}

// block = 256 threads, 1024 elements/block. Writes block-local exclusive scan
// into rowptr, block total into partials.
__global__ __launch_bounds__(256) void scanA_k(const int* __restrict__ deg,
                                               int* __restrict__ rowptr,
                                               int* __restrict__ partials, int N) {
    __shared__ int s[256];
    const int t = threadIdx.x;
    const int base = blockIdx.x * 1024;
    int v[4];
    int idx = base + t * 4;
#pragma unroll
    for (int i = 0; i < 4; ++i) v[i] = (idx + i < N) ? deg[idx + i] : 0;
    int sum = v[0] + v[1] + v[2] + v[3];
    s[t] = sum;
    __syncthreads();
    for (int off = 1; off < 256; off <<= 1) {
        int x = (t >= off) ? s[t - off] : 0;
        __syncthreads();
        s[t] += x;
        __syncthreads();
    }
    int run = s[t] - sum;  // exclusive prefix of this thread within block
#pragma unroll
    for (int i = 0; i < 4; ++i) {
        if (idx + i < N) rowptr[idx + i] = run;
        run += v[i];
    }
    if (t == 255) partials[blockIdx.x] = s[255];
}

// single block: exclusive scan of partials -> poff; rowptr[N] = Etot
__global__ __launch_bounds__(256) void scanB_k(const int* __restrict__ partials,
                                               int* __restrict__ poff,
                                               int* __restrict__ rowptr, int nb,
                                               int N, int Etot) {
    __shared__ int s[256];
    const int t = threadIdx.x;
    int v = (t < nb) ? partials[t] : 0;
    s[t] = v;
    __syncthreads();
    for (int off = 1; off < 256; off <<= 1) {
        int x = (t >= off) ? s[t - off] : 0;
        __syncthreads();
        s[t] += x;
        __syncthreads();
    }
    poff[t] = s[t] - v;
    if (t == 0) rowptr[N] = Etot;
}

__global__ void scanC_k(int* __restrict__ rowptr, const int* __restrict__ poff,
                        int* __restrict__ wp, int N) {
    int i = blockIdx.x * blockDim.x + threadIdx.x;
    if (i >= N) return;
    int r = rowptr[i] + poff[i >> 10];
    rowptr[i] = r;
    wp[i] = r;
}

__global__ void scatter_k(const int* __restrict__ ei, int E, int Etot,
                          int* __restrict__ wp, int* __restrict__ srcs) {
    int e = blockIdx.x * blockDim.x + threadIdx.x;
    if (e >= Etot) return;
    int src, dst; edge_sd(ei, E, e, src, dst);
    int pos = atomicAdd(&wp[dst], 1);
    srcs[pos] = src;
}

// ========= conv1 fused gather: online softmax + aggregate + bias + ELU =========
// one wave per dst node; lane = output channel (H=8,C=8 -> 64 ch)
__global__ __launch_bounds__(256) void agg1_csr_k(const int* __restrict__ rowptr,
                                                  const int* __restrict__ srcs,
                                                  const float* __restrict__ S,
                                                  const float* __restrict__ D,
                                                  const float* __restrict__ H,
                                                  const float* __restrict__ bias,
                                                  float* __restrict__ out, int N) {
    const int wid = (blockIdx.x * 256 + threadIdx.x) >> 6;  // dst node
    const int lane = threadIdx.x & 63;
    if (wid >= N) return;
    const int beg = rowptr[wid], end = rowptr[wid + 1];

    float dv[8];
    {
        const float4* dp = (const float4*)(D + (size_t)wid * 8);
        float4 a = dp[0], b = dp[1];
        dv[0] = a.x; dv[1] = a.y; dv[2] = a.z; dv[3] = a.w;
        dv[4] = b.x; dv[5] = b.y; dv[6] = b.z; dv[7] = b.w;
    }

    // phase 1: per-head online max/sum, lanes stride over edges
    float m[8], ss[8];
#pragma unroll
    for (int h = 0; h < 8; ++h) { m[h] = -1e30f; ss[h] = 0.0f; }
    for (int i = beg + lane; i < end; i += 64) {
        int src = srcs[i];
        const float4* sp = (const float4*)(S + (size_t)src * 8);
        float4 a = sp[0], b = sp[1];
        float sv[8] = {a.x, a.y, a.z, a.w, b.x, b.y, b.z, b.w};
#pragma unroll
        for (int h = 0; h < 8; ++h) {
            float al = leaky(sv[h] + dv[h]);
            if (al > m[h]) { ss[h] = ss[h] * __expf(m[h] - al) + 1.0f; m[h] = al; }
            else           { ss[h] += __expf(al - m[h]); }
        }
    }
#pragma unroll
    for (int off = 32; off > 0; off >>= 1) {
#pragma unroll
        for (int h = 0; h < 8; ++h) {
            float mo = __shfl_xor(m[h], off);
            float so = __shfl_xor(ss[h], off);
            float mn = fmaxf(m[h], mo);
            ss[h] = ss[h] * __expf(m[h] - mn) + so * __expf(mo - mn);
            m[h] = mn;
        }
    }

    // phase 2: gather weighted messages; lane owns channel `lane`, head lane>>3
    const int h = lane >> 3;
    const float mh = m[h];
    const float rden = 1.0f / (ss[h] + 1e-16f);
    const float dvh = dv[h];
    float acc = 0.0f;
    for (int i = beg; i < end; ++i) {
        int src = srcs[i];
        float al = leaky(S[(size_t)src * 8 + h] + dvh);
        float w = __expf(al - mh) * rden;
        acc += w * H[(size_t)src * 64 + lane];
    }
    out[(size_t)wid * 64 + lane] = elu(acc + bias[lane]);
}

// ========= conv2 fused gather (H=1,C=128): one wave per dst, 2 ch/lane =========
__global__ __launch_bounds__(256) void agg2_csr_k(const int* __restrict__ rowptr,
                                                  const int* __restrict__ srcs,
                                                  const float* __restrict__ S,
                                                  const float* __restrict__ D,
                                                  const float* __restrict__ H,
                                                  const float* __restrict__ bias,
                                                  float* __restrict__ out, int N) {
    const int wid = (blockIdx.x * 256 + threadIdx.x) >> 6;
    const int lane = threadIdx.x & 63;
    if (wid >= N) return;
    const int beg = rowptr[wid], end = rowptr[wid + 1];
    const float dvh = D[wid];

    float m = -1e30f, ss = 0.0f;
    for (int i = beg + lane; i < end; i += 64) {
        float al = leaky(S[srcs[i]] + dvh);
        if (al > m) { ss = ss * __expf(m - al) + 1.0f; m = al; }
        else        { ss += __expf(al - m); }
    }
#pragma unroll
    for (int off = 32; off > 0; off >>= 1) {
        float mo = __shfl_xor(m, off);
        float so = __shfl_xor(ss, off);
        float mn = fmaxf(m, mo);
        ss = ss * __expf(m - mn) + so * __expf(mo - mn);
        m = mn;
    }
    const float rden = 1.0f / (ss + 1e-16f);

    float acc0 = 0.0f, acc1 = 0.0f;
    for (int i = beg; i < end; ++i) {
        int src = srcs[i];
        float al = leaky(S[src] + dvh);
        float w = __expf(al - m) * rden;
        const float* row = H + (size_t)src * 128;
        acc0 += w * row[lane];
        acc1 += w * row[lane + 64];
    }
    out[(size_t)wid * 128 + lane]      = elu(acc0 + bias[lane]);
    out[(size_t)wid * 128 + lane + 64] = elu(acc1 + bias[lane + 64]);
}

extern "C" void kernel_launch(void* const* d_in, const int* in_sizes, int n_in,
                              void* d_out, int out_size, void* d_ws, size_t ws_size,
                              hipStream_t stream) {
    const float* x   = (const float*)d_in[0];
    const int*   ei  = (const int*)d_in[1];
    const float* W1  = (const float*)d_in[2];
    const float* as1 = (const float*)d_in[3];
    const float* ad1 = (const float*)d_in[4];
    const float* b1  = (const float*)d_in[5];
    const float* W2  = (const float*)d_in[6];
    const float* as2 = (const float*)d_in[7];
    const float* ad2 = (const float*)d_in[8];
    const float* b2  = (const float*)d_in[9];

    const int N = in_sizes[0] / 512;
    const int E = in_sizes[1] / 2;
    const int Etot = E + N;
    float* out = (float*)d_out;

    // ---- persistent workspace (fp32 words / ints) ----
    float* h1     = (float*)d_ws;                          // N*64
    float* s1     = h1 + (size_t)N * 64;                   // N*8
    float* d1     = s1 + (size_t)N * 8;                    // N*8
    float* out1   = d1 + (size_t)N * 8;                    // N*64
    float* h2     = out1 + (size_t)N * 64;                 // N*128
    float* s2     = h2 + (size_t)N * 128;                  // N
    float* d2     = s2 + N;                                // N
    int*   rowptr = (int*)(d2 + N);                        // N+1
    int*   srcs   = rowptr + (N + 1);                      // Etot
    // ---- transient CSR-build scratch aliased into h2 (consumed before gemm2) ----
    int* deg      = (int*)h2;          // N
    int* wp       = deg + N;           // N
    int* partials = wp + N;            // 256
    int* poff     = partials + 256;    // 256

    const int B = 256;
    const int nb = (N + 1023) / 1024;

    // CSR build
    hipMemsetAsync(deg, 0, (size_t)N * 4, stream);
    deg_k<<<(Etot + B - 1) / B, B, 0, stream>>>(ei, E, Etot, deg);
    scanA_k<<<nb, B, 0, stream>>>(deg, rowptr, partials, N);
    scanB_k<<<1, B, 0, stream>>>(partials, poff, rowptr, nb, N, Etot);
    scanC_k<<<(N + B - 1) / B, B, 0, stream>>>(rowptr, poff, wp, N);
    scatter_k<<<(Etot + B - 1) / B, B, 0, stream>>>(ei, E, Etot, wp, srcs);

    // layer 1
    gemm1_k<<<(N + 63) / 64, B, 0, stream>>>(x, W1, h1, N);
    s1d1_k<<<(N * 8 + B - 1) / B, B, 0, stream>>>(h1, as1, ad1, s1, d1, N);
    agg1_csr_k<<<(N + 3) / 4, B, 0, stream>>>(rowptr, srcs, s1, d1, h1, b1, out1, N);

    // layer 2
    gemm2_k<<<(N + 63) / 64, B, 0, stream>>>(out1, W2, h2, N);
    s2d2_k<<<(N * 64 + B - 1) / B, B, 0, stream>>>(h2, as2, ad2, s2, d2, N);
    agg2_csr_k<<<(N + 3) / 4, B, 0, stream>>>(rowptr, srcs, s2, d2, h2, b2, out, N);
}

// Round 3
// 482.419 us; speedup vs baseline: 3.1471x; 1.1209x over previous
//
#include <hip/hip_runtime.h>

#define NEG_SLOPE 0.2f

__device__ __forceinline__ float leaky(float v) {
    return v > 0.0f ? v : NEG_SLOPE * v;
}
__device__ __forceinline__ float elu(float v) {
    return v > 0.0f ? v : (__expf(v) - 1.0f);
}

// ================= GEMM1: H[N,64] = X[N,512] @ W[512,64] =================
__global__ __launch_bounds__(256) void gemm1_k(const float* __restrict__ X,
                                               const float* __restrict__ W,
                                               float* __restrict__ H, int N) {
    __shared__ float As[64][20];
    __shared__ float Bs[16][64];
    const int t = threadIdx.x;
    const int tx = t & 15, ty = t >> 4;
    const int r0 = blockIdx.x * 64;
    float acc[4][4] = {};

    for (int k0 = 0; k0 < 512; k0 += 16) {
        {
            int r = t >> 2, cg = (t & 3) * 4;
            int row = r0 + r; if (row >= N) row = N - 1;
            float4 v = *(const float4*)(X + (size_t)row * 512 + k0 + cg);
            *(float4*)&As[r][cg] = v;
        }
        {
            int r = t >> 4, cg = (t & 15) * 4;
            float4 v = *(const float4*)(W + (size_t)(k0 + r) * 64 + cg);
            *(float4*)&Bs[r][cg] = v;
        }
        __syncthreads();
#pragma unroll
        for (int kk = 0; kk < 16; ++kk) {
            float a0 = As[ty * 4 + 0][kk], a1 = As[ty * 4 + 1][kk];
            float a2 = As[ty * 4 + 2][kk], a3 = As[ty * 4 + 3][kk];
            float4 b = *(float4*)&Bs[kk][tx * 4];
            acc[0][0] += a0 * b.x; acc[0][1] += a0 * b.y; acc[0][2] += a0 * b.z; acc[0][3] += a0 * b.w;
            acc[1][0] += a1 * b.x; acc[1][1] += a1 * b.y; acc[1][2] += a1 * b.z; acc[1][3] += a1 * b.w;
            acc[2][0] += a2 * b.x; acc[2][1] += a2 * b.y; acc[2][2] += a2 * b.z; acc[2][3] += a2 * b.w;
            acc[3][0] += a3 * b.x; acc[3][1] += a3 * b.y; acc[3][2] += a3 * b.z; acc[3][3] += a3 * b.w;
        }
        __syncthreads();
    }
#pragma unroll
    for (int i = 0; i < 4; ++i) {
        int row = r0 + ty * 4 + i;
        if (row < N) {
            float4 v = make_float4(acc[i][0], acc[i][1], acc[i][2], acc[i][3]);
            *(float4*)&H[(size_t)row * 64 + tx * 4] = v;
        }
    }
}

// ================= GEMM2: H2[N,128] = A[N,64] @ W[64,128] =================
__global__ __launch_bounds__(256) void gemm2_k(const float* __restrict__ X,
                                               const float* __restrict__ W,
                                               float* __restrict__ H, int N) {
    __shared__ float As[64][20];
    __shared__ float Bs[16][128];
    const int t = threadIdx.x;
    const int tx = t & 15, ty = t >> 4;
    const int r0 = blockIdx.x * 64;
    float acc[4][8] = {};

    for (int k0 = 0; k0 < 64; k0 += 16) {
        {
            int r = t >> 2, cg = (t & 3) * 4;
            int row = r0 + r; if (row >= N) row = N - 1;
            float4 v = *(const float4*)(X + (size_t)row * 64 + k0 + cg);
            *(float4*)&As[r][cg] = v;
        }
#pragma unroll
        for (int u = 0; u < 2; ++u) {
            int lin = t + u * 256;
            int r = lin >> 5, cg = (lin & 31) * 4;
            float4 v = *(const float4*)(W + (size_t)(k0 + r) * 128 + cg);
            *(float4*)&Bs[r][cg] = v;
        }
        __syncthreads();
#pragma unroll
        for (int kk = 0; kk < 16; ++kk) {
            float a[4];
#pragma unroll
            for (int i = 0; i < 4; ++i) a[i] = As[ty * 4 + i][kk];
            float4 b0 = *(float4*)&Bs[kk][tx * 8];
            float4 b1 = *(float4*)&Bs[kk][tx * 8 + 4];
#pragma unroll
            for (int i = 0; i < 4; ++i) {
                acc[i][0] += a[i] * b0.x; acc[i][1] += a[i] * b0.y;
                acc[i][2] += a[i] * b0.z; acc[i][3] += a[i] * b0.w;
                acc[i][4] += a[i] * b1.x; acc[i][5] += a[i] * b1.y;
                acc[i][6] += a[i] * b1.z; acc[i][7] += a[i] * b1.w;
            }
        }
        __syncthreads();
    }
#pragma unroll
    for (int i = 0; i < 4; ++i) {
        int row = r0 + ty * 4 + i;
        if (row < N) {
            *(float4*)&H[(size_t)row * 128 + tx * 8] =
                make_float4(acc[i][0], acc[i][1], acc[i][2], acc[i][3]);
            *(float4*)&H[(size_t)row * 128 + tx * 8 + 4] =
                make_float4(acc[i][4], acc[i][5], acc[i][6], acc[i][7]);
        }
    }
}

// ========= per-node attention dots for conv1: s[n,h], d[n,h] (H=8,C=8) =========
__global__ void s1d1_k(const float* __restrict__ H, const float* __restrict__ Asrc,
                       const float* __restrict__ Adst, float* __restrict__ S,
                       float* __restrict__ D, int N) {
    int t = blockIdx.x * blockDim.x + threadIdx.x;
    if (t >= N * 8) return;
    int n = t >> 3, h = t & 7;
    const float4* hp = (const float4*)(H + (size_t)n * 64 + h * 8);
    float4 h0 = hp[0], h1 = hp[1];
    const float4* sp = (const float4*)(Asrc + h * 8);
    const float4* dp = (const float4*)(Adst + h * 8);
    float4 a0 = sp[0], a1 = sp[1], b0 = dp[0], b1 = dp[1];
    S[t] = h0.x * a0.x + h0.y * a0.y + h0.z * a0.z + h0.w * a0.w +
           h1.x * a1.x + h1.y * a1.y + h1.z * a1.z + h1.w * a1.w;
    D[t] = h0.x * b0.x + h0.y * b0.y + h0.z * b0.z + h0.w * b0.w +
           h1.x * b1.x + h1.y * b1.y + h1.z * b1.z + h1.w * b1.w;
}

// ========= per-node attention dots for conv2 (H=1,C=128): 1 wave per node =========
__global__ void s2d2_k(const float* __restrict__ H, const float* __restrict__ Asrc,
                       const float* __restrict__ Adst, float* __restrict__ S,
                       float* __restrict__ D, int N) {
    int t = blockIdx.x * blockDim.x + threadIdx.x;
    int n = t >> 6, lane = t & 63;
    if (n >= N) return;
    const float* row = H + (size_t)n * 128;
    float s = row[lane] * Asrc[lane] + row[lane + 64] * Asrc[lane + 64];
    float d = row[lane] * Adst[lane] + row[lane + 64] * Adst[lane + 64];
#pragma unroll
    for (int off = 32; off > 0; off >>= 1) {
        s += __shfl_down(s, off);
        d += __shfl_down(d, off);
    }
    if (lane == 0) { S[n] = s; D[n] = d; }
}

// ======================= CSR build =======================
__device__ __forceinline__ void edge_sd(const int* ei, int E, int e, int& src, int& dst) {
    if (e < E) { src = ei[e]; dst = ei[E + e]; }
    else       { src = dst = e - E; }
}

__global__ void deg_k(const int* __restrict__ ei, int E, int Etot, int* __restrict__ deg) {
    int e = blockIdx.x * blockDim.x + threadIdx.x;
    if (e >= Etot) return;
    int src, dst; edge_sd(ei, E, e, src, dst);
    atomicAdd(&deg[dst], 1);
}

__global__ __launch_bounds__(256) void scanA_k(const int* __restrict__ deg,
                                               int* __restrict__ rowptr,
                                               int* __restrict__ partials, int N) {
    __shared__ int s[256];
    const int t = threadIdx.x;
    const int base = blockIdx.x * 1024;
    int v[4];
    int idx = base + t * 4;
#pragma unroll
    for (int i = 0; i < 4; ++i) v[i] = (idx + i < N) ? deg[idx + i] : 0;
    int sum = v[0] + v[1] + v[2] + v[3];
    s[t] = sum;
    __syncthreads();
    for (int off = 1; off < 256; off <<= 1) {
        int x = (t >= off) ? s[t - off] : 0;
        __syncthreads();
        s[t] += x;
        __syncthreads();
    }
    int run = s[t] - sum;
#pragma unroll
    for (int i = 0; i < 4; ++i) {
        if (idx + i < N) rowptr[idx + i] = run;
        run += v[i];
    }
    if (t == 255) partials[blockIdx.x] = s[255];
}

__global__ __launch_bounds__(256) void scanB_k(const int* __restrict__ partials,
                                               int* __restrict__ poff,
                                               int* __restrict__ rowptr, int nb,
                                               int N, int Etot) {
    __shared__ int s[256];
    const int t = threadIdx.x;
    int v = (t < nb) ? partials[t] : 0;
    s[t] = v;
    __syncthreads();
    for (int off = 1; off < 256; off <<= 1) {
        int x = (t >= off) ? s[t - off] : 0;
        __syncthreads();
        s[t] += x;
        __syncthreads();
    }
    poff[t] = s[t] - v;
    if (t == 0) rowptr[N] = Etot;
}

__global__ void scanC_k(int* __restrict__ rowptr, const int* __restrict__ poff,
                        int* __restrict__ wp, int N) {
    int i = blockIdx.x * blockDim.x + threadIdx.x;
    if (i >= N) return;
    int r = rowptr[i] + poff[i >> 10];
    rowptr[i] = r;
    wp[i] = r;
}

__global__ void scatter_k(const int* __restrict__ ei, int E, int Etot,
                          int* __restrict__ wp, int* __restrict__ srcs) {
    int e = blockIdx.x * blockDim.x + threadIdx.x;
    if (e >= Etot) return;
    int src, dst; edge_sd(ei, E, e, src, dst);
    int pos = atomicAdd(&wp[dst], 1);
    srcs[pos] = src;
}

// ========= conv1 fused gather: cooperative (edge,head) lane layout =========
// one wave per dst node. Phase 1: lane=(edge_slot=lane>>3, head=lane&7), 8
// edges/pass, reduction = 3 xor steps. Phase 2: lane owns output channel
// `lane`; weights computed once per (edge,head) and shfl-broadcast.
__global__ __launch_bounds__(256) void agg1_csr_k(const int* __restrict__ rowptr,
                                                  const int* __restrict__ srcs,
                                                  const float* __restrict__ S,
                                                  const float* __restrict__ D,
                                                  const float* __restrict__ H,
                                                  const float* __restrict__ bias,
                                                  float* __restrict__ out, int N) {
    const int wid = (blockIdx.x * 256 + threadIdx.x) >> 6;
    const int lane = threadIdx.x & 63;
    if (wid >= N) return;
    const int beg = rowptr[wid], end = rowptr[wid + 1];
    const int h = lane & 7;     // this lane's head in weight space
    const int el = lane >> 3;   // this lane's edge slot
    const float dvh = D[(size_t)wid * 8 + h];

    // ---- phase 1: online max/sum per (edge_slot, head) lane ----
    float m = -1e30f, ss = 0.0f;
    for (int base = beg; base < end; base += 8) {
        int i = base + el;
        if (i < end) {
            float al = leaky(S[(size_t)srcs[i] * 8 + h] + dvh);
            if (al > m) { ss = ss * __expf(m - al) + 1.0f; m = al; }
            else        { ss += __expf(al - m); }
        }
    }
#pragma unroll
    for (int off = 8; off < 64; off <<= 1) {
        float mo = __shfl_xor(m, off);
        float so = __shfl_xor(ss, off);
        float mn = fmaxf(m, mo);
        ss = ss * __expf(m - mn) + so * __expf(mo - mn);
        m = mn;
    }
    const float rden = 1.0f / (ss + 1e-16f);   // for head h = lane&7

    // ---- phase 2: chunk of 8 edges; lane computes w for (el, h), then
    //      broadcasts; lane accumulates output channel `lane` (head lane>>3)
    float acc = 0.0f;
    for (int base = beg; base < end; base += 8) {
        int i = base + el;
        int src_l = 0; float w_l = 0.0f;
        if (i < end) {
            src_l = srcs[i];
            float al = leaky(S[(size_t)src_l * 8 + h] + dvh);
            w_l = __expf(al - m) * rden;
        }
        const int cnt = min(8, end - base);
        for (int j = 0; j < cnt; ++j) {
            float w = __shfl(w_l, j * 8 + (lane >> 3));
            int src = __builtin_amdgcn_readfirstlane(__shfl(src_l, j * 8));
            acc += w * H[(size_t)src * 64 + lane];
        }
    }
    out[(size_t)wid * 64 + lane] = elu(acc + bias[lane]);
}

// ========= conv2 fused gather (H=1,C=128): chunked cooperative weights =========
__global__ __launch_bounds__(256) void agg2_csr_k(const int* __restrict__ rowptr,
                                                  const int* __restrict__ srcs,
                                                  const float* __restrict__ S,
                                                  const float* __restrict__ D,
                                                  const float* __restrict__ H,
                                                  const float* __restrict__ bias,
                                                  float* __restrict__ out, int N) {
    const int wid = (blockIdx.x * 256 + threadIdx.x) >> 6;
    const int lane = threadIdx.x & 63;
    if (wid >= N) return;
    const int beg = rowptr[wid], end = rowptr[wid + 1];
    const float dvh = D[wid];

    // ---- phase 1: online softmax stats, lane = edge slot ----
    float m = -1e30f, ss = 0.0f;
    for (int base = beg; base < end; base += 64) {
        int i = base + lane;
        if (i < end) {
            float al = leaky(S[srcs[i]] + dvh);
            if (al > m) { ss = ss * __expf(m - al) + 1.0f; m = al; }
            else        { ss += __expf(al - m); }
        }
    }
#pragma unroll
    for (int off = 1; off < 64; off <<= 1) {
        float mo = __shfl_xor(m, off);
        float so = __shfl_xor(ss, off);
        float mn = fmaxf(m, mo);
        ss = ss * __expf(m - mn) + so * __expf(mo - mn);
        m = mn;
    }
    const float rden = 1.0f / (ss + 1e-16f);

    // ---- phase 2: 64-edge chunks; 1 expf per edge total ----
    float acc0 = 0.0f, acc1 = 0.0f;
    for (int base = beg; base < end; base += 64) {
        int i = base + lane;
        int src_l = 0; float w_l = 0.0f;
        if (i < end) {
            src_l = srcs[i];
            w_l = __expf(leaky(S[src_l] + dvh) - m) * rden;
        }
        const int cnt = min(64, end - base);
        for (int j = 0; j < cnt; ++j) {
            float w = __shfl(w_l, j);
            int src = __builtin_amdgcn_readfirstlane(__shfl(src_l, j));
            const float* row = H + (size_t)src * 128;
            acc0 += w * row[lane];
            acc1 += w * row[lane + 64];
        }
    }
    out[(size_t)wid * 128 + lane]      = elu(acc0 + bias[lane]);
    out[(size_t)wid * 128 + lane + 64] = elu(acc1 + bias[lane + 64]);
}

extern "C" void kernel_launch(void* const* d_in, const int* in_sizes, int n_in,
                              void* d_out, int out_size, void* d_ws, size_t ws_size,
                              hipStream_t stream) {
    const float* x   = (const float*)d_in[0];
    const int*   ei  = (const int*)d_in[1];
    const float* W1  = (const float*)d_in[2];
    const float* as1 = (const float*)d_in[3];
    const float* ad1 = (const float*)d_in[4];
    const float* b1  = (const float*)d_in[5];
    const float* W2  = (const float*)d_in[6];
    const float* as2 = (const float*)d_in[7];
    const float* ad2 = (const float*)d_in[8];
    const float* b2  = (const float*)d_in[9];

    const int N = in_sizes[0] / 512;
    const int E = in_sizes[1] / 2;
    const int Etot = E + N;
    float* out = (float*)d_out;

    // ---- persistent workspace ----
    float* h1     = (float*)d_ws;                          // N*64
    float* s1     = h1 + (size_t)N * 64;                   // N*8
    float* d1     = s1 + (size_t)N * 8;                    // N*8
    float* out1   = d1 + (size_t)N * 8;                    // N*64
    float* h2     = out1 + (size_t)N * 64;                 // N*128
    float* s2     = h2 + (size_t)N * 128;                  // N
    float* d2     = s2 + N;                                // N
    int*   rowptr = (int*)(d2 + N);                        // N+1
    int*   srcs   = rowptr + (N + 1);                      // Etot
    // ---- transient CSR-build scratch aliased into h2 (consumed before gemm2) ----
    int* deg      = (int*)h2;          // N
    int* wp       = deg + N;           // N
    int* partials = wp + N;            // 256
    int* poff     = partials + 256;    // 256

    const int B = 256;
    const int nb = (N + 1023) / 1024;

    // CSR build
    hipMemsetAsync(deg, 0, (size_t)N * 4, stream);
    deg_k<<<(Etot + B - 1) / B, B, 0, stream>>>(ei, E, Etot, deg);
    scanA_k<<<nb, B, 0, stream>>>(deg, rowptr, partials, N);
    scanB_k<<<1, B, 0, stream>>>(partials, poff, rowptr, nb, N, Etot);
    scanC_k<<<(N + B - 1) / B, B, 0, stream>>>(rowptr, poff, wp, N);
    scatter_k<<<(Etot + B - 1) / B, B, 0, stream>>>(ei, E, Etot, wp, srcs);

    // layer 1
    gemm1_k<<<(N + 63) / 64, B, 0, stream>>>(x, W1, h1, N);
    s1d1_k<<<(N * 8 + B - 1) / B, B, 0, stream>>>(h1, as1, ad1, s1, d1, N);
    agg1_csr_k<<<(N + 3) / 4, B, 0, stream>>>(rowptr, srcs, s1, d1, h1, b1, out1, N);

    // layer 2
    gemm2_k<<<(N + 63) / 64, B, 0, stream>>>(out1, W2, h2, N);
    s2d2_k<<<(N * 64 + B - 1) / B, B, 0, stream>>>(h2, as2, ad2, s2, d2, N);
    agg2_csr_k<<<(N + 3) / 4, B, 0, stream>>>(rowptr, srcs, s2, d2, h2, b2, out, N);
}

// Round 4
// 405.798 us; speedup vs baseline: 3.7413x; 1.1888x over previous
//
#include <hip/hip_runtime.h>

#define NEG_SLOPE 0.2f

__device__ __forceinline__ float leaky(float v) {
    return v > 0.0f ? v : NEG_SLOPE * v;
}
__device__ __forceinline__ float elu(float v) {
    return v > 0.0f ? v : (__expf(v) - 1.0f);
}
// fp32 -> bf16 (RNE) and pack helpers
__device__ __forceinline__ unsigned b2u(float f) {
    unsigned u = __float_as_uint(f);
    return (u + 0x7fffu + ((u >> 16) & 1u)) >> 16;
}
__device__ __forceinline__ unsigned pack2(float a, float b) {
    return b2u(a) | (b2u(b) << 16);
}
__device__ __forceinline__ float bf2f(unsigned short v) {
    return __uint_as_float(((unsigned)v) << 16);
}

// ========== GEMM1 + fused attention dots: h1b(bf16), S1, D1 ==========
// H[N,64] = X[N,512] @ W[512,64]; S1[n,h]=h.a_src, D1[n,h]=h.a_dst
__global__ __launch_bounds__(256) void gemm1_k(const float* __restrict__ X,
                                               const float* __restrict__ W,
                                               const float* __restrict__ Asrc,
                                               const float* __restrict__ Adst,
                                               unsigned short* __restrict__ Hb,
                                               float* __restrict__ S,
                                               float* __restrict__ D, int N) {
    __shared__ float As[64][20];
    __shared__ float Bs[16][64];
    const int t = threadIdx.x;
    const int tx = t & 15, ty = t >> 4;
    const int r0 = blockIdx.x * 64;
    float acc[4][4] = {};

    for (int k0 = 0; k0 < 512; k0 += 16) {
        {
            int r = t >> 2, cg = (t & 3) * 4;
            int row = r0 + r; if (row >= N) row = N - 1;
            float4 v = *(const float4*)(X + (size_t)row * 512 + k0 + cg);
            *(float4*)&As[r][cg] = v;
        }
        {
            int r = t >> 4, cg = (t & 15) * 4;
            float4 v = *(const float4*)(W + (size_t)(k0 + r) * 64 + cg);
            *(float4*)&Bs[r][cg] = v;
        }
        __syncthreads();
#pragma unroll
        for (int kk = 0; kk < 16; ++kk) {
            float a0 = As[ty * 4 + 0][kk], a1 = As[ty * 4 + 1][kk];
            float a2 = As[ty * 4 + 2][kk], a3 = As[ty * 4 + 3][kk];
            float4 b = *(float4*)&Bs[kk][tx * 4];
            acc[0][0] += a0 * b.x; acc[0][1] += a0 * b.y; acc[0][2] += a0 * b.z; acc[0][3] += a0 * b.w;
            acc[1][0] += a1 * b.x; acc[1][1] += a1 * b.y; acc[1][2] += a1 * b.z; acc[1][3] += a1 * b.w;
            acc[2][0] += a2 * b.x; acc[2][1] += a2 * b.y; acc[2][2] += a2 * b.z; acc[2][3] += a2 * b.w;
            acc[3][0] += a3 * b.x; acc[3][1] += a3 * b.y; acc[3][2] += a3 * b.z; acc[3][3] += a3 * b.w;
        }
        __syncthreads();
    }

    float as_[4], ad_[4];
#pragma unroll
    for (int j = 0; j < 4; ++j) { as_[j] = Asrc[tx * 4 + j]; ad_[j] = Adst[tx * 4 + j]; }
#pragma unroll
    for (int i = 0; i < 4; ++i) {
        int row = r0 + ty * 4 + i;
        bool ok = row < N;
        if (ok) {
            uint2 pk;
            pk.x = pack2(acc[i][0], acc[i][1]);
            pk.y = pack2(acc[i][2], acc[i][3]);
            *(uint2*)(Hb + (size_t)row * 64 + tx * 4) = pk;
        }
        float ps = acc[i][0] * as_[0] + acc[i][1] * as_[1] + acc[i][2] * as_[2] + acc[i][3] * as_[3];
        float pd = acc[i][0] * ad_[0] + acc[i][1] * ad_[1] + acc[i][2] * ad_[2] + acc[i][3] * ad_[3];
        ps += __shfl_xor(ps, 1);   // pair (tx, tx^1) covers the 8 channels of head tx>>1
        pd += __shfl_xor(pd, 1);
        if (ok && !(tx & 1)) {
            S[(size_t)row * 8 + (tx >> 1)] = ps;
            D[(size_t)row * 8 + (tx >> 1)] = pd;
        }
    }
}

// ========== GEMM2 + fused attention dots: h2b(bf16), S2, D2 ==========
// H2[N,128] = A[N,64] @ W[64,128]; S2[n]=h2.a_src2, D2[n]=h2.a_dst2
__global__ __launch_bounds__(256) void gemm2_k(const float* __restrict__ X,
                                               const float* __restrict__ W,
                                               const float* __restrict__ Asrc,
                                               const float* __restrict__ Adst,
                                               unsigned short* __restrict__ Hb,
                                               float* __restrict__ S,
                                               float* __restrict__ D, int N) {
    __shared__ float As[64][20];
    __shared__ float Bs[16][128];
    const int t = threadIdx.x;
    const int tx = t & 15, ty = t >> 4;
    const int r0 = blockIdx.x * 64;
    float acc[4][8] = {};

    for (int k0 = 0; k0 < 64; k0 += 16) {
        {
            int r = t >> 2, cg = (t & 3) * 4;
            int row = r0 + r; if (row >= N) row = N - 1;
            float4 v = *(const float4*)(X + (size_t)row * 64 + k0 + cg);
            *(float4*)&As[r][cg] = v;
        }
#pragma unroll
        for (int u = 0; u < 2; ++u) {
            int lin = t + u * 256;
            int r = lin >> 5, cg = (lin & 31) * 4;
            float4 v = *(const float4*)(W + (size_t)(k0 + r) * 128 + cg);
            *(float4*)&Bs[r][cg] = v;
        }
        __syncthreads();
#pragma unroll
        for (int kk = 0; kk < 16; ++kk) {
            float a[4];
#pragma unroll
            for (int i = 0; i < 4; ++i) a[i] = As[ty * 4 + i][kk];
            float4 b0 = *(float4*)&Bs[kk][tx * 8];
            float4 b1 = *(float4*)&Bs[kk][tx * 8 + 4];
#pragma unroll
            for (int i = 0; i < 4; ++i) {
                acc[i][0] += a[i] * b0.x; acc[i][1] += a[i] * b0.y;
                acc[i][2] += a[i] * b0.z; acc[i][3] += a[i] * b0.w;
                acc[i][4] += a[i] * b1.x; acc[i][5] += a[i] * b1.y;
                acc[i][6] += a[i] * b1.z; acc[i][7] += a[i] * b1.w;
            }
        }
        __syncthreads();
    }

    float as_[8], ad_[8];
#pragma unroll
    for (int j = 0; j < 8; ++j) { as_[j] = Asrc[tx * 8 + j]; ad_[j] = Adst[tx * 8 + j]; }
#pragma unroll
    for (int i = 0; i < 4; ++i) {
        int row = r0 + ty * 4 + i;
        bool ok = row < N;
        if (ok) {
            uint4 pk;
            pk.x = pack2(acc[i][0], acc[i][1]);
            pk.y = pack2(acc[i][2], acc[i][3]);
            pk.z = pack2(acc[i][4], acc[i][5]);
            pk.w = pack2(acc[i][6], acc[i][7]);
            *(uint4*)(Hb + (size_t)row * 128 + tx * 8) = pk;
        }
        float ps = 0.0f, pd = 0.0f;
#pragma unroll
        for (int j = 0; j < 8; ++j) { ps += acc[i][j] * as_[j]; pd += acc[i][j] * ad_[j]; }
#pragma unroll
        for (int off = 1; off < 16; off <<= 1) {
            ps += __shfl_xor(ps, off);
            pd += __shfl_xor(pd, off);
        }
        if (ok && tx == 0) { S[row] = ps; D[row] = pd; }
    }
}

// ======================= CSR build =======================
__device__ __forceinline__ void edge_sd(const int* ei, int E, int e, int& src, int& dst) {
    if (e < E) { src = ei[e]; dst = ei[E + e]; }
    else       { src = dst = e - E; }
}

__global__ void deg_k(const int* __restrict__ ei, int E, int Etot, int* __restrict__ deg) {
    int e = blockIdx.x * blockDim.x + threadIdx.x;
    if (e >= Etot) return;
    int src, dst; edge_sd(ei, E, e, src, dst);
    atomicAdd(&deg[dst], 1);
}

__global__ __launch_bounds__(256) void scanA_k(const int* __restrict__ deg,
                                               int* __restrict__ rowptr,
                                               int* __restrict__ partials, int N) {
    __shared__ int s[256];
    const int t = threadIdx.x;
    const int base = blockIdx.x * 1024;
    int v[4];
    int idx = base + t * 4;
#pragma unroll
    for (int i = 0; i < 4; ++i) v[i] = (idx + i < N) ? deg[idx + i] : 0;
    int sum = v[0] + v[1] + v[2] + v[3];
    s[t] = sum;
    __syncthreads();
    for (int off = 1; off < 256; off <<= 1) {
        int x = (t >= off) ? s[t - off] : 0;
        __syncthreads();
        s[t] += x;
        __syncthreads();
    }
    int run = s[t] - sum;
#pragma unroll
    for (int i = 0; i < 4; ++i) {
        if (idx + i < N) rowptr[idx + i] = run;
        run += v[i];
    }
    if (t == 255) partials[blockIdx.x] = s[255];
}

__global__ __launch_bounds__(256) void scanB_k(const int* __restrict__ partials,
                                               int* __restrict__ poff,
                                               int* __restrict__ rowptr, int nb,
                                               int N, int Etot) {
    __shared__ int s[256];
    const int t = threadIdx.x;
    int v = (t < nb) ? partials[t] : 0;
    s[t] = v;
    __syncthreads();
    for (int off = 1; off < 256; off <<= 1) {
        int x = (t >= off) ? s[t - off] : 0;
        __syncthreads();
        s[t] += x;
        __syncthreads();
    }
    poff[t] = s[t] - v;
    if (t == 0) rowptr[N] = Etot;
}

__global__ void scanC_k(int* __restrict__ rowptr, const int* __restrict__ poff,
                        int* __restrict__ wp, int N) {
    int i = blockIdx.x * blockDim.x + threadIdx.x;
    if (i >= N) return;
    int r = rowptr[i] + poff[i >> 10];
    rowptr[i] = r;
    wp[i] = r;
}

__global__ void scatter_k(const int* __restrict__ ei, int E, int Etot,
                          int* __restrict__ wp, int* __restrict__ srcs) {
    int e = blockIdx.x * blockDim.x + threadIdx.x;
    if (e >= Etot) return;
    int src, dst; edge_sd(ei, E, e, src, dst);
    int pos = atomicAdd(&wp[dst], 1);
    srcs[pos] = src;
}

// ========= conv1 fused gather, bf16 payload, branch-free unrolled =========
__global__ __launch_bounds__(256) void agg1_csr_k(const int* __restrict__ rowptr,
                                                  const int* __restrict__ srcs,
                                                  const float* __restrict__ S,
                                                  const float* __restrict__ D,
                                                  const unsigned short* __restrict__ Hb,
                                                  const float* __restrict__ bias,
                                                  float* __restrict__ out, int N) {
    const int wid = (blockIdx.x * 256 + threadIdx.x) >> 6;
    const int lane = threadIdx.x & 63;
    if (wid >= N) return;
    const int beg = rowptr[wid], end = rowptr[wid + 1];
    const int h = lane & 7;     // weight-space head
    const int el = lane >> 3;   // weight-space edge slot
    const float dvh = D[(size_t)wid * 8 + h];

    // phase 1: online max/sum per (edge_slot, head) lane; 3-step reduction
    float m = -1e30f, ss = 0.0f;
    for (int base = beg; base < end; base += 8) {
        int i = base + el;
        if (i < end) {
            float al = leaky(S[(size_t)srcs[i] * 8 + h] + dvh);
            if (al > m) { ss = ss * __expf(m - al) + 1.0f; m = al; }
            else        { ss += __expf(al - m); }
        }
    }
#pragma unroll
    for (int off = 8; off < 64; off <<= 1) {
        float mo = __shfl_xor(m, off);
        float so = __shfl_xor(ss, off);
        float mn = fmaxf(m, mo);
        ss = ss * __expf(m - mn) + so * __expf(mo - mn);
        m = mn;
    }
    const float rden = 1.0f / (ss + 1e-16f);

    // phase 2: 8-edge chunks, fully unrolled predicated loads (8 in flight)
    float acc = 0.0f;
    for (int base = beg; base < end; base += 8) {
        int i = base + el;
        int src_l = 0; float w_l = 0.0f;
        if (i < end) {
            src_l = srcs[i];
            w_l = __expf(leaky(S[(size_t)src_l * 8 + h] + dvh) - m) * rden;
        }
#pragma unroll
        for (int j = 0; j < 8; ++j) {
            float w = __shfl(w_l, j * 8 + (lane >> 3));
            int src = __builtin_amdgcn_readfirstlane(__shfl(src_l, j * 8));
            acc += w * bf2f(Hb[(size_t)src * 64 + lane]);
        }
    }
    out[(size_t)wid * 64 + lane] = elu(acc + bias[lane]);
}

// ========= conv2 fused gather, bf16 payload (lane = 2 adjacent channels) =========
__global__ __launch_bounds__(256) void agg2_csr_k(const int* __restrict__ rowptr,
                                                  const int* __restrict__ srcs,
                                                  const float* __restrict__ S,
                                                  const float* __restrict__ D,
                                                  const unsigned short* __restrict__ Hb,
                                                  const float* __restrict__ bias,
                                                  float* __restrict__ out, int N) {
    const int wid = (blockIdx.x * 256 + threadIdx.x) >> 6;
    const int lane = threadIdx.x & 63;
    if (wid >= N) return;
    const int beg = rowptr[wid], end = rowptr[wid + 1];
    const float dvh = D[wid];
    const int c0 = lane * 2;

    // phase 1: online softmax stats, lane = edge slot
    float m = -1e30f, ss = 0.0f;
    for (int base = beg; base < end; base += 64) {
        int i = base + lane;
        if (i < end) {
            float al = leaky(S[srcs[i]] + dvh);
            if (al > m) { ss = ss * __expf(m - al) + 1.0f; m = al; }
            else        { ss += __expf(al - m); }
        }
    }
#pragma unroll
    for (int off = 1; off < 64; off <<= 1) {
        float mo = __shfl_xor(m, off);
        float so = __shfl_xor(ss, off);
        float mn = fmaxf(m, mo);
        ss = ss * __expf(m - mn) + so * __expf(mo - mn);
        m = mn;
    }
    const float rden = 1.0f / (ss + 1e-16f);

    // phase 2: 64-edge chunks, x4 unrolled predicated loads
    float acc0 = 0.0f, acc1 = 0.0f;
    for (int base = beg; base < end; base += 64) {
        int i = base + lane;
        int src_l = 0; float w_l = 0.0f;
        if (i < end) {
            src_l = srcs[i];
            w_l = __expf(leaky(S[src_l] + dvh) - m) * rden;
        }
        const int cnt = min(64, end - base);
        for (int j0 = 0; j0 < cnt; j0 += 4) {
#pragma unroll
            for (int u = 0; u < 4; ++u) {
                int j = j0 + u;                       // j>=cnt lanes carry w=0
                float w = __shfl(w_l, j);
                int src = __builtin_amdgcn_readfirstlane(__shfl(src_l, j));
                unsigned p = *(const unsigned*)(Hb + (size_t)src * 128 + c0);
                acc0 += w * __uint_as_float(p << 16);
                acc1 += w * __uint_as_float(p & 0xffff0000u);
            }
        }
    }
    float2 o;
    o.x = elu(acc0 + bias[c0]);
    o.y = elu(acc1 + bias[c0 + 1]);
    *(float2*)(out + (size_t)wid * 128 + c0) = o;
}

extern "C" void kernel_launch(void* const* d_in, const int* in_sizes, int n_in,
                              void* d_out, int out_size, void* d_ws, size_t ws_size,
                              hipStream_t stream) {
    const float* x   = (const float*)d_in[0];
    const int*   ei  = (const int*)d_in[1];
    const float* W1  = (const float*)d_in[2];
    const float* as1 = (const float*)d_in[3];
    const float* ad1 = (const float*)d_in[4];
    const float* b1  = (const float*)d_in[5];
    const float* W2  = (const float*)d_in[6];
    const float* as2 = (const float*)d_in[7];
    const float* ad2 = (const float*)d_in[8];
    const float* b2  = (const float*)d_in[9];

    const int N = in_sizes[0] / 512;
    const int E = in_sizes[1] / 2;
    const int Etot = E + N;
    float* out = (float*)d_out;

    // ---- persistent workspace ----
    float*          out1   = (float*)d_ws;                       // N*64 fp32
    unsigned short* h1b    = (unsigned short*)(out1 + (size_t)N * 64);  // N*64 bf16
    float*          s1     = (float*)(h1b + (size_t)N * 64);     // N*8
    float*          d1     = s1 + (size_t)N * 8;                 // N*8
    unsigned short* h2b    = (unsigned short*)(d1 + (size_t)N * 8);     // N*128 bf16
    float*          s2     = (float*)(h2b + (size_t)N * 128);    // N
    float*          d2     = s2 + N;                             // N
    int*            rowptr = (int*)(d2 + N);                     // N+1
    int*            srcs   = rowptr + (N + 1);                   // Etot
    // transient CSR scratch aliased into h2b (dead before gemm2 writes it)
    int* deg      = (int*)h2b;         // N
    int* wp       = deg + N;           // N
    int* partials = wp + N;            // 256
    int* poff     = partials + 256;    // 256

    const int B = 256;
    const int nb = (N + 1023) / 1024;

    // CSR build
    hipMemsetAsync(deg, 0, (size_t)N * 4, stream);
    deg_k<<<(Etot + B - 1) / B, B, 0, stream>>>(ei, E, Etot, deg);
    scanA_k<<<nb, B, 0, stream>>>(deg, rowptr, partials, N);
    scanB_k<<<1, B, 0, stream>>>(partials, poff, rowptr, nb, N, Etot);
    scanC_k<<<(N + B - 1) / B, B, 0, stream>>>(rowptr, poff, wp, N);
    scatter_k<<<(Etot + B - 1) / B, B, 0, stream>>>(ei, E, Etot, wp, srcs);

    // layer 1
    gemm1_k<<<(N + 63) / 64, B, 0, stream>>>(x, W1, as1, ad1, h1b, s1, d1, N);
    agg1_csr_k<<<(N + 3) / 4, B, 0, stream>>>(rowptr, srcs, s1, d1, h1b, b1, out1, N);

    // layer 2
    gemm2_k<<<(N + 63) / 64, B, 0, stream>>>(out1, W2, as2, ad2, h2b, s2, d2, N);
    agg2_csr_k<<<(N + 3) / 4, B, 0, stream>>>(rowptr, srcs, s2, d2, h2b, b2, out, N);
}

// Round 5
// 390.997 us; speedup vs baseline: 3.8829x; 1.0379x over previous
//
#include <hip/hip_runtime.h>

#define NEG_SLOPE 0.2f

typedef __attribute__((ext_vector_type(8))) short bf16x8;
typedef __attribute__((ext_vector_type(4))) float f32x4;

__device__ __forceinline__ float leaky(float v) {
    return v > 0.0f ? v : NEG_SLOPE * v;
}
__device__ __forceinline__ float elu(float v) {
    return v > 0.0f ? v : (__expf(v) - 1.0f);
}
// fp32 -> bf16 round-half-up (2 VALU); statistically equivalent to RNE here
__device__ __forceinline__ short f2b(float f) {
    return (short)((__float_as_uint(f) + 0x8000u) >> 16);
}
__device__ __forceinline__ float bf2f(unsigned short v) {
    return __uint_as_float(((unsigned)v) << 16);
}
__device__ __forceinline__ float blo(unsigned u) { return __uint_as_float(u << 16); }
__device__ __forceinline__ float bhi(unsigned u) { return __uint_as_float(u & 0xffff0000u); }

// ===== weight swizzle into MFMA B-frag order: lane=(kk>>3)*16+n, reg=kk&7 =====
// Ws[((kt*ntiles + nt)*64 + lane)*8 + j] = bf16(W[k][n]),  kt=k>>5, kk=k&31
__global__ void wswz_k(const float* __restrict__ W, unsigned short* __restrict__ Ws,
                       int K, int lgN) {
    int i = blockIdx.x * 256 + threadIdx.x;
    if (i >= (K << lgN)) return;
    int k = i >> lgN, n = i & ((1 << lgN) - 1);
    int kt = k >> 5, kk = k & 31;
    int nt = n >> 4, nn = n & 15;
    int ntiles = 1 << (lgN - 4);
    int lane = (kk >> 3) * 16 + nn, j = kk & 7;
    Ws[(((size_t)(kt * ntiles + nt)) * 64 + lane) * 8 + j] = (unsigned short)f2b(W[i]);
}

// ========== GEMM1 (MFMA bf16): h1b[N,64] = bf16(X[N,512] @ W1[512,64]) ==========
// LDS-free: A-frags from global fp32 + in-reg cvt; B-frags from swizzled Ws (L2-hit).
__global__ __launch_bounds__(256) void gemm1_k(const float* __restrict__ X,
                                               const unsigned short* __restrict__ Ws,
                                               unsigned short* __restrict__ Hb, int N) {
    const int lane = threadIdx.x & 63;
    const int wave = threadIdx.x >> 6;
    const int m0 = blockIdx.x * 64 + wave * 16;
    const int q = lane >> 4, lc = lane & 15;
    const int arow = m0 + lc;
    const float* xrow = X + (size_t)min(arow, N - 1) * 512 + q * 8;
    const bf16x8* bW = (const bf16x8*)Ws;

    f32x4 acc[4] = {{0.f,0.f,0.f,0.f},{0.f,0.f,0.f,0.f},{0.f,0.f,0.f,0.f},{0.f,0.f,0.f,0.f}};

    for (int kt = 0; kt < 16; ++kt) {
        float4 a0 = *(const float4*)(xrow + kt * 32);
        float4 a1 = *(const float4*)(xrow + kt * 32 + 4);
        bf16x8 af;
        af[0] = f2b(a0.x); af[1] = f2b(a0.y); af[2] = f2b(a0.z); af[3] = f2b(a0.w);
        af[4] = f2b(a1.x); af[5] = f2b(a1.y); af[6] = f2b(a1.z); af[7] = f2b(a1.w);
#pragma unroll
        for (int nt = 0; nt < 4; ++nt) {
            bf16x8 bf = bW[(size_t)(kt * 4 + nt) * 64 + lane];
            acc[nt] = __builtin_amdgcn_mfma_f32_16x16x32_bf16(af, bf, acc[nt], 0, 0, 0);
        }
    }
    // C/D: row = m0 + q*4 + r, col = nt*16 + lc   [verified mapping]
#pragma unroll
    for (int r = 0; r < 4; ++r) {
        int row = m0 + q * 4 + r;
        if (row < N) {
#pragma unroll
            for (int nt = 0; nt < 4; ++nt)
                Hb[(size_t)row * 64 + nt * 16 + lc] = (unsigned short)f2b(acc[nt][r]);
        }
    }
}

// ========== GEMM2 (MFMA bf16): h2b[N,128] = bf16(out1[N,64] @ W2[64,128]) ==========
__global__ __launch_bounds__(256) void gemm2_k(const float* __restrict__ X,
                                               const unsigned short* __restrict__ Ws,
                                               unsigned short* __restrict__ Hb, int N) {
    const int lane = threadIdx.x & 63;
    const int wave = threadIdx.x >> 6;
    const int m0 = blockIdx.x * 64 + wave * 16;
    const int q = lane >> 4, lc = lane & 15;
    const int arow = m0 + lc;
    const float* xrow = X + (size_t)min(arow, N - 1) * 64 + q * 8;
    const bf16x8* bW = (const bf16x8*)Ws;

    f32x4 acc[8] = {{0.f,0.f,0.f,0.f},{0.f,0.f,0.f,0.f},{0.f,0.f,0.f,0.f},{0.f,0.f,0.f,0.f},
                    {0.f,0.f,0.f,0.f},{0.f,0.f,0.f,0.f},{0.f,0.f,0.f,0.f},{0.f,0.f,0.f,0.f}};

#pragma unroll
    for (int kt = 0; kt < 2; ++kt) {
        float4 a0 = *(const float4*)(xrow + kt * 32);
        float4 a1 = *(const float4*)(xrow + kt * 32 + 4);
        bf16x8 af;
        af[0] = f2b(a0.x); af[1] = f2b(a0.y); af[2] = f2b(a0.z); af[3] = f2b(a0.w);
        af[4] = f2b(a1.x); af[5] = f2b(a1.y); af[6] = f2b(a1.z); af[7] = f2b(a1.w);
#pragma unroll
        for (int nt = 0; nt < 8; ++nt) {
            bf16x8 bf = bW[(size_t)(kt * 8 + nt) * 64 + lane];
            acc[nt] = __builtin_amdgcn_mfma_f32_16x16x32_bf16(af, bf, acc[nt], 0, 0, 0);
        }
    }
#pragma unroll
    for (int r = 0; r < 4; ++r) {
        int row = m0 + q * 4 + r;
        if (row < N) {
#pragma unroll
            for (int nt = 0; nt < 8; ++nt)
                Hb[(size_t)row * 128 + nt * 16 + lc] = (unsigned short)f2b(acc[nt][r]);
        }
    }
}

// ========= attention dots conv1 from bf16 payload: S/D [N,8] =========
__global__ void s1d1_k(const unsigned short* __restrict__ Hb, const float* __restrict__ Asrc,
                       const float* __restrict__ Adst, float* __restrict__ S,
                       float* __restrict__ D, int N) {
    int t = blockIdx.x * blockDim.x + threadIdx.x;
    if (t >= N * 8) return;
    int n = t >> 3, h = t & 7;
    uint4 p = *(const uint4*)(Hb + (size_t)n * 64 + h * 8);
    float hv[8] = {blo(p.x), bhi(p.x), blo(p.y), bhi(p.y),
                   blo(p.z), bhi(p.z), blo(p.w), bhi(p.w)};
    const float* as_ = Asrc + h * 8;
    const float* ad_ = Adst + h * 8;
    float s = 0.f, d = 0.f;
#pragma unroll
    for (int j = 0; j < 8; ++j) { s += hv[j] * as_[j]; d += hv[j] * ad_[j]; }
    S[t] = s; D[t] = d;
}

// ========= attention dots conv2 from bf16 payload: S/D [N] =========
__global__ void s2d2_k(const unsigned short* __restrict__ Hb, const float* __restrict__ Asrc,
                       const float* __restrict__ Adst, float* __restrict__ S,
                       float* __restrict__ D, int N) {
    int t = blockIdx.x * blockDim.x + threadIdx.x;
    int n = t >> 6, lane = t & 63;
    if (n >= N) return;
    const unsigned short* row = Hb + (size_t)n * 128;
    float v0 = bf2f(row[lane]), v1 = bf2f(row[lane + 64]);
    float s = v0 * Asrc[lane] + v1 * Asrc[lane + 64];
    float d = v0 * Adst[lane] + v1 * Adst[lane + 64];
#pragma unroll
    for (int off = 32; off > 0; off >>= 1) {
        s += __shfl_down(s, off);
        d += __shfl_down(d, off);
    }
    if (lane == 0) { S[n] = s; D[n] = d; }
}

// ======================= CSR build =======================
__device__ __forceinline__ void edge_sd(const int* ei, int E, int e, int& src, int& dst) {
    if (e < E) { src = ei[e]; dst = ei[E + e]; }
    else       { src = dst = e - E; }
}

__global__ void deg_k(const int* __restrict__ ei, int E, int Etot, int* __restrict__ deg) {
    int e = blockIdx.x * blockDim.x + threadIdx.x;
    if (e >= Etot) return;
    int src, dst; edge_sd(ei, E, e, src, dst);
    atomicAdd(&deg[dst], 1);
}

__global__ __launch_bounds__(256) void scanA_k(const int* __restrict__ deg,
                                               int* __restrict__ rowptr,
                                               int* __restrict__ partials, int N) {
    __shared__ int s[256];
    const int t = threadIdx.x;
    const int base = blockIdx.x * 1024;
    int v[4];
    int idx = base + t * 4;
#pragma unroll
    for (int i = 0; i < 4; ++i) v[i] = (idx + i < N) ? deg[idx + i] : 0;
    int sum = v[0] + v[1] + v[2] + v[3];
    s[t] = sum;
    __syncthreads();
    for (int off = 1; off < 256; off <<= 1) {
        int x = (t >= off) ? s[t - off] : 0;
        __syncthreads();
        s[t] += x;
        __syncthreads();
    }
    int run = s[t] - sum;
#pragma unroll
    for (int i = 0; i < 4; ++i) {
        if (idx + i < N) rowptr[idx + i] = run;
        run += v[i];
    }
    if (t == 255) partials[blockIdx.x] = s[255];
}

__global__ __launch_bounds__(256) void scanB_k(const int* __restrict__ partials,
                                               int* __restrict__ poff,
                                               int* __restrict__ rowptr, int nb,
                                               int N, int Etot) {
    __shared__ int s[256];
    const int t = threadIdx.x;
    int v = (t < nb) ? partials[t] : 0;
    s[t] = v;
    __syncthreads();
    for (int off = 1; off < 256; off <<= 1) {
        int x = (t >= off) ? s[t - off] : 0;
        __syncthreads();
        s[t] += x;
        __syncthreads();
    }
    poff[t] = s[t] - v;
    if (t == 0) rowptr[N] = Etot;
}

__global__ void scanC_k(int* __restrict__ rowptr, const int* __restrict__ poff,
                        int* __restrict__ wp, int N) {
    int i = blockIdx.x * blockDim.x + threadIdx.x;
    if (i >= N) return;
    int r = rowptr[i] + poff[i >> 10];
    rowptr[i] = r;
    wp[i] = r;
}

__global__ void scatter_k(const int* __restrict__ ei, int E, int Etot,
                          int* __restrict__ wp, int* __restrict__ srcs) {
    int e = blockIdx.x * blockDim.x + threadIdx.x;
    if (e >= Etot) return;
    int src, dst; edge_sd(ei, E, e, src, dst);
    int pos = atomicAdd(&wp[dst], 1);
    srcs[pos] = src;
}

// ========= conv1 fused gather, bf16 payload, branch-free unrolled =========
__global__ __launch_bounds__(256) void agg1_csr_k(const int* __restrict__ rowptr,
                                                  const int* __restrict__ srcs,
                                                  const float* __restrict__ S,
                                                  const float* __restrict__ D,
                                                  const unsigned short* __restrict__ Hb,
                                                  const float* __restrict__ bias,
                                                  float* __restrict__ out, int N) {
    const int wid = (blockIdx.x * 256 + threadIdx.x) >> 6;
    const int lane = threadIdx.x & 63;
    if (wid >= N) return;
    const int beg = rowptr[wid], end = rowptr[wid + 1];
    const int h = lane & 7;
    const int el = lane >> 3;
    const float dvh = D[(size_t)wid * 8 + h];

    float m = -1e30f, ss = 0.0f;
    for (int base = beg; base < end; base += 8) {
        int i = base + el;
        if (i < end) {
            float al = leaky(S[(size_t)srcs[i] * 8 + h] + dvh);
            if (al > m) { ss = ss * __expf(m - al) + 1.0f; m = al; }
            else        { ss += __expf(al - m); }
        }
    }
#pragma unroll
    for (int off = 8; off < 64; off <<= 1) {
        float mo = __shfl_xor(m, off);
        float so = __shfl_xor(ss, off);
        float mn = fmaxf(m, mo);
        ss = ss * __expf(m - mn) + so * __expf(mo - mn);
        m = mn;
    }
    const float rden = 1.0f / (ss + 1e-16f);

    float acc = 0.0f;
    for (int base = beg; base < end; base += 8) {
        int i = base + el;
        int src_l = 0; float w_l = 0.0f;
        if (i < end) {
            src_l = srcs[i];
            w_l = __expf(leaky(S[(size_t)src_l * 8 + h] + dvh) - m) * rden;
        }
#pragma unroll
        for (int j = 0; j < 8; ++j) {
            float w = __shfl(w_l, j * 8 + (lane >> 3));
            int src = __builtin_amdgcn_readfirstlane(__shfl(src_l, j * 8));
            acc += w * bf2f(Hb[(size_t)src * 64 + lane]);
        }
    }
    out[(size_t)wid * 64 + lane] = elu(acc + bias[lane]);
}

// ========= conv2 fused gather, bf16 payload (lane = 2 adjacent channels) =========
__global__ __launch_bounds__(256) void agg2_csr_k(const int* __restrict__ rowptr,
                                                  const int* __restrict__ srcs,
                                                  const float* __restrict__ S,
                                                  const float* __restrict__ D,
                                                  const unsigned short* __restrict__ Hb,
                                                  const float* __restrict__ bias,
                                                  float* __restrict__ out, int N) {
    const int wid = (blockIdx.x * 256 + threadIdx.x) >> 6;
    const int lane = threadIdx.x & 63;
    if (wid >= N) return;
    const int beg = rowptr[wid], end = rowptr[wid + 1];
    const float dvh = D[wid];
    const int c0 = lane * 2;

    float m = -1e30f, ss = 0.0f;
    for (int base = beg; base < end; base += 64) {
        int i = base + lane;
        if (i < end) {
            float al = leaky(S[srcs[i]] + dvh);
            if (al > m) { ss = ss * __expf(m - al) + 1.0f; m = al; }
            else        { ss += __expf(al - m); }
        }
    }
#pragma unroll
    for (int off = 1; off < 64; off <<= 1) {
        float mo = __shfl_xor(m, off);
        float so = __shfl_xor(ss, off);
        float mn = fmaxf(m, mo);
        ss = ss * __expf(m - mn) + so * __expf(mo - mn);
        m = mn;
    }
    const float rden = 1.0f / (ss + 1e-16f);

    float acc0 = 0.0f, acc1 = 0.0f;
    for (int base = beg; base < end; base += 64) {
        int i = base + lane;
        int src_l = 0; float w_l = 0.0f;
        if (i < end) {
            src_l = srcs[i];
            w_l = __expf(leaky(S[src_l] + dvh) - m) * rden;
        }
        const int cnt = min(64, end - base);
        for (int j0 = 0; j0 < cnt; j0 += 4) {
#pragma unroll
            for (int u = 0; u < 4; ++u) {
                int j = j0 + u;
                float w = __shfl(w_l, j);
                int src = __builtin_amdgcn_readfirstlane(__shfl(src_l, j));
                unsigned p = *(const unsigned*)(Hb + (size_t)src * 128 + c0);
                acc0 += w * __uint_as_float(p << 16);
                acc1 += w * __uint_as_float(p & 0xffff0000u);
            }
        }
    }
    float2 o;
    o.x = elu(acc0 + bias[c0]);
    o.y = elu(acc1 + bias[c0 + 1]);
    *(float2*)(out + (size_t)wid * 128 + c0) = o;
}

extern "C" void kernel_launch(void* const* d_in, const int* in_sizes, int n_in,
                              void* d_out, int out_size, void* d_ws, size_t ws_size,
                              hipStream_t stream) {
    const float* x   = (const float*)d_in[0];
    const int*   ei  = (const int*)d_in[1];
    const float* W1  = (const float*)d_in[2];
    const float* as1 = (const float*)d_in[3];
    const float* ad1 = (const float*)d_in[4];
    const float* b1  = (const float*)d_in[5];
    const float* W2  = (const float*)d_in[6];
    const float* as2 = (const float*)d_in[7];
    const float* ad2 = (const float*)d_in[8];
    const float* b2  = (const float*)d_in[9];

    const int N = in_sizes[0] / 512;
    const int E = in_sizes[1] / 2;
    const int Etot = E + N;
    float* out = (float*)d_out;

    // ---- workspace layout (w-swizzled weights first for 16B alignment) ----
    unsigned short* w1s    = (unsigned short*)d_ws;               // 512*64 bf16 = 64 KB
    unsigned short* w2s    = w1s + 512 * 64;                      // 64*128 bf16 = 16 KB
    float*          out1   = (float*)(w2s + 64 * 128);            // N*64 fp32
    unsigned short* h1b    = (unsigned short*)(out1 + (size_t)N * 64);  // N*64 bf16
    float*          s1     = (float*)(h1b + (size_t)N * 64);      // N*8
    float*          d1     = s1 + (size_t)N * 8;                  // N*8
    unsigned short* h2b    = (unsigned short*)(d1 + (size_t)N * 8);     // N*128 bf16
    float*          s2     = (float*)(h2b + (size_t)N * 128);     // N
    float*          d2     = s2 + N;                              // N
    int*            rowptr = (int*)(d2 + N);                      // N+1
    int*            srcs   = rowptr + (N + 1);                    // Etot
    // transient CSR scratch aliased into h2b (dead before gemm2 writes it)
    int* deg      = (int*)h2b;         // N
    int* wp       = deg + N;           // N
    int* partials = wp + N;            // 256
    int* poff     = partials + 256;    // 256

    const int B = 256;
    const int nb = (N + 1023) / 1024;
    const int gblk = (N + 63) / 64;

    // CSR build
    hipMemsetAsync(deg, 0, (size_t)N * 4, stream);
    deg_k<<<(Etot + B - 1) / B, B, 0, stream>>>(ei, E, Etot, deg);
    scanA_k<<<nb, B, 0, stream>>>(deg, rowptr, partials, N);
    scanB_k<<<1, B, 0, stream>>>(partials, poff, rowptr, nb, N, Etot);
    scanC_k<<<(N + B - 1) / B, B, 0, stream>>>(rowptr, poff, wp, N);
    scatter_k<<<(Etot + B - 1) / B, B, 0, stream>>>(ei, E, Etot, wp, srcs);

    // weight swizzles (bf16 B-frag order)
    wswz_k<<<(512 * 64 + B - 1) / B, B, 0, stream>>>(W1, w1s, 512, 6);
    wswz_k<<<(64 * 128 + B - 1) / B, B, 0, stream>>>(W2, w2s, 64, 7);

    // layer 1
    gemm1_k<<<gblk, B, 0, stream>>>(x, w1s, h1b, N);
    s1d1_k<<<(N * 8 + B - 1) / B, B, 0, stream>>>(h1b, as1, ad1, s1, d1, N);
    agg1_csr_k<<<(N + 3) / 4, B, 0, stream>>>(rowptr, srcs, s1, d1, h1b, b1, out1, N);

    // layer 2
    gemm2_k<<<gblk, B, 0, stream>>>(out1, w2s, h2b, N);
    s2d2_k<<<(N * 64 + B - 1) / B, B, 0, stream>>>(h2b, as2, ad2, s2, d2, N);
    agg2_csr_k<<<(N + 3) / 4, B, 0, stream>>>(rowptr, srcs, s2, d2, h2b, b2, out, N);
}

// Round 7
// 368.122 us; speedup vs baseline: 4.1242x; 1.0621x over previous
//
#include <hip/hip_runtime.h>

#define NEG_SLOPE 0.2f

typedef __attribute__((ext_vector_type(8))) short bf16x8;
typedef __attribute__((ext_vector_type(4))) float f32x4;

__device__ __forceinline__ float leaky(float v) {
    return v > 0.0f ? v : NEG_SLOPE * v;
}
__device__ __forceinline__ float elu(float v) {
    return v > 0.0f ? v : (__expf(v) - 1.0f);
}
__device__ __forceinline__ short f2b(float f) {
    return (short)((__float_as_uint(f) + 0x8000u) >> 16);
}
__device__ __forceinline__ float bf2f(unsigned short v) {
    return __uint_as_float(((unsigned)v) << 16);
}

// ===== prep: zero deg + swizzle both weights into MFMA B-frag order =====
// B-frag: lane=(kk>>3)*16+nn, reg=kk&7 per 32x16 (KxN) tile.
__global__ void prep_k(const float* __restrict__ W1, const float* __restrict__ W2,
                       unsigned short* __restrict__ w1s, unsigned short* __restrict__ w2s,
                       int* __restrict__ deg, int N) {
    int i = blockIdx.x * 256 + threadIdx.x;
    if (i < N) deg[i] = 0;
    if (i < 512 * 64) {                       // W1: K=512, N=64
        int k = i >> 6, n = i & 63;
        int kt = k >> 5, kk = k & 31;
        int nt = n >> 4, nn = n & 15;
        int lane = (kk >> 3) * 16 + nn, j = kk & 7;
        w1s[(((size_t)(kt * 4 + nt)) * 64 + lane) * 8 + j] = (unsigned short)f2b(W1[i]);
    } else if (i < 512 * 64 + 64 * 128) {     // W2: K=64, N=128
        int i2 = i - 512 * 64;
        int k = i2 >> 7, n = i2 & 127;
        int kt = k >> 5, kk = k & 31;
        int nt = n >> 4, nn = n & 15;
        int lane = (kk >> 3) * 16 + nn, j = kk & 7;
        w2s[(((size_t)(kt * 8 + nt)) * 64 + lane) * 8 + j] = (unsigned short)f2b(W2[i2]);  // FIXED: was W2[i]
    }
}

// ========== GEMM1 (MFMA bf16) + fused attention dots ==========
// h1b[N,64] = bf16(X[N,512] @ W1), S1[n,h], D1[n,h]
__global__ __launch_bounds__(256) void gemm1_k(const float* __restrict__ X,
                                               const unsigned short* __restrict__ Ws,
                                               const float* __restrict__ Asrc,
                                               const float* __restrict__ Adst,
                                               unsigned short* __restrict__ Hb,
                                               float* __restrict__ S,
                                               float* __restrict__ D, int N) {
    const int lane = threadIdx.x & 63;
    const int wave = threadIdx.x >> 6;
    const int m0 = blockIdx.x * 64 + wave * 16;
    const int q = lane >> 4, lc = lane & 15;
    const int arow = m0 + lc;
    const float* xrow = X + (size_t)min(arow, N - 1) * 512 + q * 8;
    const bf16x8* bW = (const bf16x8*)Ws;

    f32x4 acc[4] = {{0.f,0.f,0.f,0.f},{0.f,0.f,0.f,0.f},{0.f,0.f,0.f,0.f},{0.f,0.f,0.f,0.f}};

    for (int kt = 0; kt < 16; ++kt) {
        float4 a0 = *(const float4*)(xrow + kt * 32);
        float4 a1 = *(const float4*)(xrow + kt * 32 + 4);
        bf16x8 af;
        af[0] = f2b(a0.x); af[1] = f2b(a0.y); af[2] = f2b(a0.z); af[3] = f2b(a0.w);
        af[4] = f2b(a1.x); af[5] = f2b(a1.y); af[6] = f2b(a1.z); af[7] = f2b(a1.w);
#pragma unroll
        for (int nt = 0; nt < 4; ++nt) {
            bf16x8 bf = bW[(size_t)(kt * 4 + nt) * 64 + lane];
            acc[nt] = __builtin_amdgcn_mfma_f32_16x16x32_bf16(af, bf, acc[nt], 0, 0, 0);
        }
    }

    // att vectors indexed flat by col (att[h][c] = A[h*8+c] = A[col])
    float asc[4], adc[4];
#pragma unroll
    for (int nt = 0; nt < 4; ++nt) { asc[nt] = Asrc[nt * 16 + lc]; adc[nt] = Adst[nt * 16 + lc]; }

    // C/D: row = m0+q*4+r, col = nt*16+lc; head(col)=2nt+(lc>>3)
#pragma unroll
    for (int r = 0; r < 4; ++r) {
        int row = m0 + q * 4 + r;
        bool ok = row < N;
        if (ok) {
#pragma unroll
            for (int nt = 0; nt < 4; ++nt)
                Hb[(size_t)row * 64 + nt * 16 + lc] = (unsigned short)f2b(acc[nt][r]);
        }
        float ps[4], pd[4];
#pragma unroll
        for (int nt = 0; nt < 4; ++nt) { ps[nt] = acc[nt][r] * asc[nt]; pd[nt] = acc[nt][r] * adc[nt]; }
#pragma unroll
        for (int off = 1; off < 8; off <<= 1) {
#pragma unroll
            for (int nt = 0; nt < 4; ++nt) {
                ps[nt] += __shfl_xor(ps[nt], off);
                pd[nt] += __shfl_xor(pd[nt], off);
            }
        }
        if (ok && !(lc & 7)) {
            int hb = lc >> 3;
#pragma unroll
            for (int nt = 0; nt < 4; ++nt) {
                S[(size_t)row * 8 + nt * 2 + hb] = ps[nt];
                D[(size_t)row * 8 + nt * 2 + hb] = pd[nt];
            }
        }
    }
}

// ========== GEMM2 (MFMA bf16) + fused attention dots ==========
// h2b[N,128] = bf16(out1[N,64] @ W2), S2[n], D2[n]
__global__ __launch_bounds__(256) void gemm2_k(const float* __restrict__ X,
                                               const unsigned short* __restrict__ Ws,
                                               const float* __restrict__ Asrc,
                                               const float* __restrict__ Adst,
                                               unsigned short* __restrict__ Hb,
                                               float* __restrict__ S,
                                               float* __restrict__ D, int N) {
    const int lane = threadIdx.x & 63;
    const int wave = threadIdx.x >> 6;
    const int m0 = blockIdx.x * 64 + wave * 16;
    const int q = lane >> 4, lc = lane & 15;
    const int arow = m0 + lc;
    const float* xrow = X + (size_t)min(arow, N - 1) * 64 + q * 8;
    const bf16x8* bW = (const bf16x8*)Ws;

    f32x4 acc[8] = {{0.f,0.f,0.f,0.f},{0.f,0.f,0.f,0.f},{0.f,0.f,0.f,0.f},{0.f,0.f,0.f,0.f},
                    {0.f,0.f,0.f,0.f},{0.f,0.f,0.f,0.f},{0.f,0.f,0.f,0.f},{0.f,0.f,0.f,0.f}};

#pragma unroll
    for (int kt = 0; kt < 2; ++kt) {
        float4 a0 = *(const float4*)(xrow + kt * 32);
        float4 a1 = *(const float4*)(xrow + kt * 32 + 4);
        bf16x8 af;
        af[0] = f2b(a0.x); af[1] = f2b(a0.y); af[2] = f2b(a0.z); af[3] = f2b(a0.w);
        af[4] = f2b(a1.x); af[5] = f2b(a1.y); af[6] = f2b(a1.z); af[7] = f2b(a1.w);
#pragma unroll
        for (int nt = 0; nt < 8; ++nt) {
            bf16x8 bf = bW[(size_t)(kt * 8 + nt) * 64 + lane];
            acc[nt] = __builtin_amdgcn_mfma_f32_16x16x32_bf16(af, bf, acc[nt], 0, 0, 0);
        }
    }

    float asc[8], adc[8];
#pragma unroll
    for (int nt = 0; nt < 8; ++nt) { asc[nt] = Asrc[nt * 16 + lc]; adc[nt] = Adst[nt * 16 + lc]; }

#pragma unroll
    for (int r = 0; r < 4; ++r) {
        int row = m0 + q * 4 + r;
        bool ok = row < N;
        if (ok) {
#pragma unroll
            for (int nt = 0; nt < 8; ++nt)
                Hb[(size_t)row * 128 + nt * 16 + lc] = (unsigned short)f2b(acc[nt][r]);
        }
        float ps = 0.f, pd = 0.f;
#pragma unroll
        for (int nt = 0; nt < 8; ++nt) { ps += acc[nt][r] * asc[nt]; pd += acc[nt][r] * adc[nt]; }
#pragma unroll
        for (int off = 1; off < 16; off <<= 1) {
            ps += __shfl_xor(ps, off);
            pd += __shfl_xor(pd, off);
        }
        if (ok && lc == 0) { S[row] = ps; D[row] = pd; }
    }
}

// ======================= CSR build =======================
__device__ __forceinline__ void edge_sd(const int* ei, int E, int e, int& src, int& dst) {
    if (e < E) { src = ei[e]; dst = ei[E + e]; }
    else       { src = dst = e - E; }
}

__global__ void deg_k(const int* __restrict__ ei, int E, int Etot, int* __restrict__ deg) {
    int e = blockIdx.x * blockDim.x + threadIdx.x;
    if (e >= Etot) return;
    int src, dst; edge_sd(ei, E, e, src, dst);
    atomicAdd(&deg[dst], 1);
}

__global__ __launch_bounds__(256) void scanA_k(const int* __restrict__ deg,
                                               int* __restrict__ rowptr,
                                               int* __restrict__ partials, int N) {
    __shared__ int s[256];
    const int t = threadIdx.x;
    const int base = blockIdx.x * 1024;
    int v[4];
    int idx = base + t * 4;
#pragma unroll
    for (int i = 0; i < 4; ++i) v[i] = (idx + i < N) ? deg[idx + i] : 0;
    int sum = v[0] + v[1] + v[2] + v[3];
    s[t] = sum;
    __syncthreads();
    for (int off = 1; off < 256; off <<= 1) {
        int x = (t >= off) ? s[t - off] : 0;
        __syncthreads();
        s[t] += x;
        __syncthreads();
    }
    int run = s[t] - sum;
#pragma unroll
    for (int i = 0; i < 4; ++i) {
        if (idx + i < N) rowptr[idx + i] = run;
        run += v[i];
    }
    if (t == 255) partials[blockIdx.x] = s[255];
}

__global__ __launch_bounds__(256) void scanB_k(const int* __restrict__ partials,
                                               int* __restrict__ poff,
                                               int* __restrict__ rowptr, int nb,
                                               int N, int Etot) {
    __shared__ int s[256];
    const int t = threadIdx.x;
    int v = (t < nb) ? partials[t] : 0;
    s[t] = v;
    __syncthreads();
    for (int off = 1; off < 256; off <<= 1) {
        int x = (t >= off) ? s[t - off] : 0;
        __syncthreads();
        s[t] += x;
        __syncthreads();
    }
    poff[t] = s[t] - v;
    if (t == 0) rowptr[N] = Etot;
}

__global__ void scanC_k(int* __restrict__ rowptr, const int* __restrict__ poff,
                        int* __restrict__ wp, int N) {
    int i = blockIdx.x * blockDim.x + threadIdx.x;
    if (i >= N) return;
    int r = rowptr[i] + poff[i >> 10];
    rowptr[i] = r;
    wp[i] = r;
}

__global__ void scatter_k(const int* __restrict__ ei, int E, int Etot,
                          int* __restrict__ wp, int* __restrict__ srcs) {
    int e = blockIdx.x * blockDim.x + threadIdx.x;
    if (e >= Etot) return;
    int src, dst; edge_sd(ei, E, e, src, dst);
    int pos = atomicAdd(&wp[dst], 1);
    srcs[pos] = src;
}

// ========= conv1 gather: max-only phase1, fused num/den phase2 =========
__global__ __launch_bounds__(256) void agg1_csr_k(const int* __restrict__ rowptr,
                                                  const int* __restrict__ srcs,
                                                  const float* __restrict__ S,
                                                  const float* __restrict__ D,
                                                  const unsigned short* __restrict__ Hb,
                                                  const float* __restrict__ bias,
                                                  float* __restrict__ out, int N) {
    const int wid = (blockIdx.x * 256 + threadIdx.x) >> 6;
    const int lane = threadIdx.x & 63;
    if (wid >= N) return;
    const int beg = rowptr[wid], end = rowptr[wid + 1];
    const int h = lane & 7;     // weight-space head
    const int el = lane >> 3;   // weight-space edge slot
    const float dvh = D[(size_t)wid * 8 + h];

    // phase 1: pure max (no expf)
    float m = -1e30f;
    for (int i = beg + el; i < end; i += 8)
        m = fmaxf(m, leaky(S[(size_t)srcs[i] * 8 + h] + dvh));
#pragma unroll
    for (int off = 8; off < 64; off <<= 1)
        m = fmaxf(m, __shfl_xor(m, off));

    // phase 2: unnormalized numerator (channel space) + denominator (weight space)
    float acc = 0.0f, den = 0.0f;
    for (int base = beg; base < end; base += 8) {
        int i = base + el;
        int src_l = 0; float w_l = 0.0f;
        if (i < end) {
            src_l = srcs[i];
            w_l = __expf(leaky(S[(size_t)src_l * 8 + h] + dvh) - m);
        }
        den += w_l;
#pragma unroll
        for (int j = 0; j < 8; ++j) {
            float w = __shfl(w_l, j * 8 + (lane >> 3));
            int src = __builtin_amdgcn_readfirstlane(__shfl(src_l, j * 8));
            acc += w * bf2f(Hb[(size_t)src * 64 + lane]);
        }
    }
#pragma unroll
    for (int off = 8; off < 64; off <<= 1)
        den += __shfl_xor(den, off);
    // lane (channel c=lane) needs den of head c>>3; lane k<8 holds head k
    float rden = 1.0f / (__shfl(den, lane >> 3) + 1e-16f);
    out[(size_t)wid * 64 + lane] = elu(acc * rden + bias[lane]);
}

// ========= conv2 gather: max-only phase1, fused num/den phase2 =========
__global__ __launch_bounds__(256) void agg2_csr_k(const int* __restrict__ rowptr,
                                                  const int* __restrict__ srcs,
                                                  const float* __restrict__ S,
                                                  const float* __restrict__ D,
                                                  const unsigned short* __restrict__ Hb,
                                                  const float* __restrict__ bias,
                                                  float* __restrict__ out, int N) {
    const int wid = (blockIdx.x * 256 + threadIdx.x) >> 6;
    const int lane = threadIdx.x & 63;
    if (wid >= N) return;
    const int beg = rowptr[wid], end = rowptr[wid + 1];
    const float dvh = D[wid];
    const int c0 = lane * 2;

    // phase 1: pure max
    float m = -1e30f;
    for (int i = beg + lane; i < end; i += 64)
        m = fmaxf(m, leaky(S[srcs[i]] + dvh));
#pragma unroll
    for (int off = 1; off < 64; off <<= 1)
        m = fmaxf(m, __shfl_xor(m, off));

    // phase 2
    float acc0 = 0.0f, acc1 = 0.0f, den = 0.0f;
    for (int base = beg; base < end; base += 64) {
        int i = base + lane;
        int src_l = 0; float w_l = 0.0f;
        if (i < end) {
            src_l = srcs[i];
            w_l = __expf(leaky(S[src_l] + dvh) - m);
        }
        den += w_l;
        const int cnt = min(64, end - base);
        for (int j0 = 0; j0 < cnt; j0 += 4) {
#pragma unroll
            for (int u = 0; u < 4; ++u) {
                int j = j0 + u;                 // j>=cnt lanes carry w=0
                float w = __shfl(w_l, j);
                int src = __builtin_amdgcn_readfirstlane(__shfl(src_l, j));
                unsigned p = *(const unsigned*)(Hb + (size_t)src * 128 + c0);
                acc0 += w * __uint_as_float(p << 16);
                acc1 += w * __uint_as_float(p & 0xffff0000u);
            }
        }
    }
#pragma unroll
    for (int off = 1; off < 64; off <<= 1)
        den += __shfl_xor(den, off);
    const float rden = 1.0f / (den + 1e-16f);
    float2 o;
    o.x = elu(acc0 * rden + bias[c0]);
    o.y = elu(acc1 * rden + bias[c0 + 1]);
    *(float2*)(out + (size_t)wid * 128 + c0) = o;
}

extern "C" void kernel_launch(void* const* d_in, const int* in_sizes, int n_in,
                              void* d_out, int out_size, void* d_ws, size_t ws_size,
                              hipStream_t stream) {
    const float* x   = (const float*)d_in[0];
    const int*   ei  = (const int*)d_in[1];
    const float* W1  = (const float*)d_in[2];
    const float* as1 = (const float*)d_in[3];
    const float* ad1 = (const float*)d_in[4];
    const float* b1  = (const float*)d_in[5];
    const float* W2  = (const float*)d_in[6];
    const float* as2 = (const float*)d_in[7];
    const float* ad2 = (const float*)d_in[8];
    const float* b2  = (const float*)d_in[9];

    const int N = in_sizes[0] / 512;
    const int E = in_sizes[1] / 2;
    const int Etot = E + N;
    float* out = (float*)d_out;

    // ---- workspace layout ----
    unsigned short* w1s    = (unsigned short*)d_ws;               // 512*64 bf16
    unsigned short* w2s    = w1s + 512 * 64;                      // 64*128 bf16
    float*          out1   = (float*)(w2s + 64 * 128);            // N*64 fp32
    unsigned short* h1b    = (unsigned short*)(out1 + (size_t)N * 64);  // N*64 bf16
    float*          s1     = (float*)(h1b + (size_t)N * 64);      // N*8
    float*          d1     = s1 + (size_t)N * 8;                  // N*8
    unsigned short* h2b    = (unsigned short*)(d1 + (size_t)N * 8);     // N*128 bf16
    float*          s2     = (float*)(h2b + (size_t)N * 128);     // N
    float*          d2     = s2 + N;                              // N
    int*            rowptr = (int*)(d2 + N);                      // N+1
    int*            srcs   = rowptr + (N + 1);                    // Etot
    // transient CSR scratch aliased into h2b (dead before gemm2 writes it)
    int* deg      = (int*)h2b;         // N
    int* wp       = deg + N;           // N
    int* partials = wp + N;            // 256
    int* poff     = partials + 256;    // 256

    const int B = 256;
    const int nb = (N + 1023) / 1024;
    const int gblk = (N + 63) / 64;
    const int prep_n = (N > 512 * 64 + 64 * 128) ? N : (512 * 64 + 64 * 128);

    prep_k<<<(prep_n + B - 1) / B, B, 0, stream>>>(W1, W2, w1s, w2s, deg, N);
    deg_k<<<(Etot + B - 1) / B, B, 0, stream>>>(ei, E, Etot, deg);
    scanA_k<<<nb, B, 0, stream>>>(deg, rowptr, partials, N);
    scanB_k<<<1, B, 0, stream>>>(partials, poff, rowptr, nb, N, Etot);
    scanC_k<<<(N + B - 1) / B, B, 0, stream>>>(rowptr, poff, wp, N);
    scatter_k<<<(Etot + B - 1) / B, B, 0, stream>>>(ei, E, Etot, wp, srcs);

    gemm1_k<<<gblk, B, 0, stream>>>(x, w1s, as1, ad1, h1b, s1, d1, N);
    agg1_csr_k<<<(N + 3) / 4, B, 0, stream>>>(rowptr, srcs, s1, d1, h1b, b1, out1, N);

    gemm2_k<<<gblk, B, 0, stream>>>(out1, w2s, as2, ad2, h2b, s2, d2, N);
    agg2_csr_k<<<(N + 3) / 4, B, 0, stream>>>(rowptr, srcs, s2, d2, h2b, b2, out, N);
}